// Round 15
// baseline (803.527 us; speedup 1.0000x reference)
//
#include <hip/hip_runtime.h>
#include <hip/hip_bf16.h>
#include <float.h>

// Problem constants (OSG_C_29987461660961)
#define NTOK 2048
#define FDIM 1024
#define HDIM 512
#define EDIM 256
#define BATCH 2
#define KSEG 30
#define NP1 2049
static const size_t ST2 = (size_t)NP1 * NP1;   // rowscan Sp per-batch element count

// ---------------------------------------------------------------------------
// NT GEMM (64x64 tile, 4x4 micro) — layer 1
// ---------------------------------------------------------------------------
__global__ __launch_bounds__(256)
void gemm_nt64(const float* __restrict__ A, int lda,
               const float* __restrict__ Bm, int ldb,
               const float* __restrict__ bias,
               float* __restrict__ C, int ldc, int K)
{
    __shared__ float As[32][68];
    __shared__ float Bs[32][68];
    const int t = threadIdx.x;
    const int tx = t & 15, ty = t >> 4;
    const int lrow = t >> 3, lkv = t & 7;
    const int by = blockIdx.y, bx = blockIdx.x;

    float acc[4][4] = {};
    const int ktiles = K >> 5;
    for (int kt = 0; kt < ktiles; ++kt) {
#pragma unroll
        for (int h = 0; h < 2; ++h) {
            const int r = lrow + h * 32;
            const float4 av = *(const float4*)(A + (size_t)(by * 64 + r) * lda + kt * 32 + lkv * 4);
            As[lkv * 4 + 0][r] = av.x; As[lkv * 4 + 1][r] = av.y;
            As[lkv * 4 + 2][r] = av.z; As[lkv * 4 + 3][r] = av.w;
            const float4 bv = *(const float4*)(Bm + (size_t)(bx * 64 + r) * ldb + kt * 32 + lkv * 4);
            Bs[lkv * 4 + 0][r] = bv.x; Bs[lkv * 4 + 1][r] = bv.y;
            Bs[lkv * 4 + 2][r] = bv.z; Bs[lkv * 4 + 3][r] = bv.w;
        }
        __syncthreads();
#pragma unroll
        for (int kk = 0; kk < 32; ++kk) {
            const float4 a = *(const float4*)&As[kk][ty * 4];
            const float4 b = *(const float4*)&Bs[kk][tx * 4];
            const float ar[4] = {a.x, a.y, a.z, a.w};
            const float br[4] = {b.x, b.y, b.z, b.w};
#pragma unroll
            for (int i = 0; i < 4; ++i)
#pragma unroll
                for (int j = 0; j < 4; ++j)
                    acc[i][j] = fmaf(ar[i], br[j], acc[i][j]);
        }
        __syncthreads();
    }

    const int row0 = by * 64 + ty * 4;
    const int col0 = bx * 64 + tx * 4;
#pragma unroll
    for (int i = 0; i < 4; ++i) {
        float4 v4;
        v4.x = acc[i][0] + bias[col0 + 0];
        v4.y = acc[i][1] + bias[col0 + 1];
        v4.z = acc[i][2] + bias[col0 + 2];
        v4.w = acc[i][3] + bias[col0 + 3];
        *(float4*)(C + (size_t)(row0 + i) * ldc + col0) = v4;
    }
}

// ---------------------------------------------------------------------------
// Split-K 128x128 / 8x8 GEMM partial for layer 0 (x @ W0^T).
// ---------------------------------------------------------------------------
__global__ __launch_bounds__(256)
void gemm_nt128s(const float* __restrict__ A, int lda,
                 const float* __restrict__ Bm, int ldb,
                 float* __restrict__ Cp, int ldc, int M, int khalf)
{
    __shared__ float As[16][140];
    __shared__ float Bs[16][140];
    const int t = threadIdx.x;
    const int tx = t & 15, ty = t >> 4;
    const int by = blockIdx.y, bx = blockIdx.x;
    const int k0 = blockIdx.z * khalf;
    const int fq = t & 3, lr = t >> 2;

    float acc[8][8] = {};
    for (int kt = 0; kt < khalf / 16; ++kt) {
#pragma unroll
        for (int h = 0; h < 2; ++h) {
            const int r = lr + h * 64;
            const int rr = r + 4 * (r >> 5);
            const float4 av = *(const float4*)(A + (size_t)(by * 128 + r) * lda + k0 + kt * 16 + fq * 4);
            As[fq * 4 + 0][rr] = av.x; As[fq * 4 + 1][rr] = av.y;
            As[fq * 4 + 2][rr] = av.z; As[fq * 4 + 3][rr] = av.w;
            const float4 bv = *(const float4*)(Bm + (size_t)(bx * 128 + r) * ldb + k0 + kt * 16 + fq * 4);
            Bs[fq * 4 + 0][rr] = bv.x; Bs[fq * 4 + 1][rr] = bv.y;
            Bs[fq * 4 + 2][rr] = bv.z; Bs[fq * 4 + 3][rr] = bv.w;
        }
        __syncthreads();
        const int ma = 8 * ty + 4 * (ty >> 2);
        const int mb = 8 * tx + 4 * (tx >> 2);
#pragma unroll
        for (int k = 0; k < 16; ++k) {
            const float4 a0 = *(const float4*)&As[k][ma];
            const float4 a1 = *(const float4*)&As[k][ma + 4];
            const float4 b0 = *(const float4*)&Bs[k][mb];
            const float4 b1 = *(const float4*)&Bs[k][mb + 4];
            const float ar[8] = {a0.x, a0.y, a0.z, a0.w, a1.x, a1.y, a1.z, a1.w};
            const float br[8] = {b0.x, b0.y, b0.z, b0.w, b1.x, b1.y, b1.z, b1.w};
#pragma unroll
            for (int i = 0; i < 8; ++i)
#pragma unroll
                for (int j = 0; j < 8; ++j)
                    acc[i][j] = fmaf(ar[i], br[j], acc[i][j]);
        }
        __syncthreads();
    }

    float* outp = Cp + (size_t)blockIdx.z * M * ldc;
    const int row0 = by * 128 + ty * 8;
    const int col0 = bx * 128 + tx * 8;
#pragma unroll
    for (int i = 0; i < 8; ++i) {
        float4 w0; w0.x = acc[i][0]; w0.y = acc[i][1]; w0.z = acc[i][2]; w0.w = acc[i][3];
        float4 w1; w1.x = acc[i][4]; w1.y = acc[i][5]; w1.z = acc[i][6]; w1.w = acc[i][7];
        *(float4*)(outp + (size_t)(row0 + i) * ldc + col0) = w0;
        *(float4*)(outp + (size_t)(row0 + i) * ldc + col0 + 4) = w1;
    }
}

// h = relu(p0 + p1 + bias)
__global__ __launch_bounds__(256)
void combine_relu(const float* __restrict__ p0, const float* __restrict__ p1,
                  const float* __restrict__ bias, float* __restrict__ hout)
{
    const int idx = blockIdx.x * 256 + threadIdx.x;
    const float4 a = ((const float4*)p0)[idx];
    const float4 b = ((const float4*)p1)[idx];
    const float4 bs = *(const float4*)&bias[(idx & 127) * 4];
    float4 o;
    o.x = fmaxf(a.x + b.x + bs.x, 0.0f);
    o.y = fmaxf(a.y + b.y + bs.y, 0.0f);
    o.z = fmaxf(a.z + b.z + bs.z, 0.0f);
    o.w = fmaxf(a.w + b.w + bs.w, 0.0f);
    ((float4*)hout)[idx] = o;
}

// ---------------------------------------------------------------------------
// Correlation GEMM + D epilogue: 128x128 tile, BK=16, 8x8 microtile.
// ---------------------------------------------------------------------------
__global__ __launch_bounds__(256)
void gemm_corr(const float* __restrict__ E, float* __restrict__ D,
               const float* __restrict__ dvec)
{
    __shared__ float As[16][140];
    __shared__ float Bs[16][140];
    const int z = blockIdx.z;
    const float* Eb = E + (size_t)z * NTOK * EDIM;
    float* Db = D + (size_t)z * NTOK * NTOK;
    const int t = threadIdx.x;
    const int tx = t & 15, ty = t >> 4;
    const int by = blockIdx.y, bx = blockIdx.x;
    const int fq = t & 3, lr = t >> 2;

    float acc[8][8] = {};
    for (int kt = 0; kt < EDIM / 16; ++kt) {
#pragma unroll
        for (int h = 0; h < 2; ++h) {
            const int r = lr + h * 64;
            const int rr = r + 4 * (r >> 5);
            const float4 av = *(const float4*)(Eb + (size_t)(by * 128 + r) * EDIM + kt * 16 + fq * 4);
            As[fq * 4 + 0][rr] = av.x; As[fq * 4 + 1][rr] = av.y;
            As[fq * 4 + 2][rr] = av.z; As[fq * 4 + 3][rr] = av.w;
            const float4 bv = *(const float4*)(Eb + (size_t)(bx * 128 + r) * EDIM + kt * 16 + fq * 4);
            Bs[fq * 4 + 0][rr] = bv.x; Bs[fq * 4 + 1][rr] = bv.y;
            Bs[fq * 4 + 2][rr] = bv.z; Bs[fq * 4 + 3][rr] = bv.w;
        }
        __syncthreads();
        const int ma = 8 * ty + 4 * (ty >> 2);
        const int mb = 8 * tx + 4 * (tx >> 2);
#pragma unroll
        for (int k = 0; k < 16; ++k) {
            const float4 a0 = *(const float4*)&As[k][ma];
            const float4 a1 = *(const float4*)&As[k][ma + 4];
            const float4 b0 = *(const float4*)&Bs[k][mb];
            const float4 b1 = *(const float4*)&Bs[k][mb + 4];
            const float ar[8] = {a0.x, a0.y, a0.z, a0.w, a1.x, a1.y, a1.z, a1.w};
            const float br[8] = {b0.x, b0.y, b0.z, b0.w, b1.x, b1.y, b1.z, b1.w};
#pragma unroll
            for (int i = 0; i < 8; ++i)
#pragma unroll
                for (int j = 0; j < 8; ++j)
                    acc[i][j] = fmaf(ar[i], br[j], acc[i][j]);
        }
        __syncthreads();
    }

    const int row0 = by * 128 + ty * 8;
    const int col0 = bx * 128 + tx * 8;
    float di[8], dj[8];
#pragma unroll
    for (int i = 0; i < 8; ++i) di[i] = dvec[z * NTOK + row0 + i];
#pragma unroll
    for (int j = 0; j < 8; ++j) dj[j] = dvec[z * NTOK + col0 + j];
#pragma unroll
    for (int i = 0; i < 8; ++i) {
        float o[8];
#pragma unroll
        for (int j = 0; j < 8; ++j) {
            const float den = sqrtf(fmaxf(di[i] * dj[j], 1e-8f));
            o[j] = 0.5f * (1.0f - acc[i][j] / den);
        }
        float4 w0; w0.x = o[0]; w0.y = o[1]; w0.z = o[2]; w0.w = o[3];
        float4 w1; w1.x = o[4]; w1.y = o[5]; w1.z = o[6]; w1.w = o[7];
        *(float4*)(Db + (size_t)(row0 + i) * NTOK + col0) = w0;
        *(float4*)(Db + (size_t)(row0 + i) * NTOK + col0 + 4) = w1;
    }
}

__global__ __launch_bounds__(256)
void rownorm_kernel(const float* __restrict__ e, float* __restrict__ dvec)
{
    const int wid = (blockIdx.x * 256 + threadIdx.x) >> 6;
    const int lane = threadIdx.x & 63;
    if (wid >= BATCH * NTOK) return;
    const float4 v = *(const float4*)(e + (size_t)wid * EDIM + lane * 4);
    float s = v.x * v.x + v.y * v.y + v.z * v.z + v.w * v.w;
#pragma unroll
    for (int off = 32; off; off >>= 1) s += __shfl_xor(s, off);
    if (lane == 0) dvec[wid] = s;
}

// Row-wise inclusive scan of D (f32) into R rows 1..N (f64). R[r][0]=0.
__global__ __launch_bounds__(256)
void sat_row_kernel(const float* __restrict__ D, double* __restrict__ R)
{
    const int b = blockIdx.y;
    const int r = blockIdx.x + 1;
    const float* drow = D + (size_t)b * NTOK * NTOK + (size_t)(r - 1) * NTOK;
    double* rrow = R + (size_t)b * ST2 + (size_t)r * NP1;
    const int t = threadIdx.x, lane = t & 63, wv = t >> 6;
    __shared__ double wtot[4];
    double carry = 0.0;
    if (t == 0) rrow[0] = 0.0;
    for (int ch = 0; ch < NTOK / 256; ++ch) {
        double v = (double)drow[ch * 256 + t];
#pragma unroll
        for (int d = 1; d < 64; d <<= 1) {
            const double u = __shfl_up(v, (unsigned)d, 64);
            if (lane >= d) v += u;
        }
        if (lane == 63) wtot[wv] = v;
        __syncthreads();
        double pre = carry;
        for (int ww = 0; ww < wv; ++ww) pre += wtot[ww];
        const double tot = carry + wtot[0] + wtot[1] + wtot[2] + wtot[3];
        rrow[ch * 256 + t + 1] = v + pre;
        __syncthreads();
        carry = tot;
    }
}

// strip sums: aux[s][c] = sum_{r in strip s} R[r][c]  (triangular: only cb >= s)
__global__ void satc1(const double* __restrict__ R, double* __restrict__ aux)
{
    const int b = blockIdx.z, s = blockIdx.y, cb = blockIdx.x;
    if (cb < s) return;                        // tt[s][c] only used when c > s*256
    const int c = cb * 256 + threadIdx.x;
    if (c > NTOK) return;
    const double* rb = R + (size_t)b * ST2;
    double tt = 0.0;
    const int r0 = s * 256 + 1;
    for (int r = r0; r < r0 + 256; ++r) tt += rb[(size_t)r * NP1 + c];
    aux[(size_t)(b * 8 + s) * NP1 + c] = tt;
}
// exclusive prefix over strips
__global__ void satc2(double* __restrict__ aux)
{
    const int b = blockIdx.y;
    const int c = blockIdx.x * 256 + threadIdx.x;
    if (c > NTOK) return;
    double run = 0.0;
    for (int s = 0; s < 8; ++s) {
        const size_t id = (size_t)(b * 8 + s) * NP1 + c;
        const double tt = aux[id]; aux[id] = run; run += tt;
    }
}
// dg[c] = final Sp[c][c] = aux[strip(c)][c] + partial rows within strip
__global__ void satc_diag(const double* __restrict__ R, const double* __restrict__ aux,
                          double* __restrict__ dg)
{
    const int b = blockIdx.y;
    const int c = blockIdx.x * 256 + threadIdx.x;
    if (c > NTOK) return;
    if (c == 0) { dg[b * NP1] = 0.0; return; }
    const int s = (c - 1) >> 8;
    const int r0 = s * 256 + 1;
    const double* rb = R + (size_t)b * ST2;
    double run = aux[(size_t)(b * 8 + s) * NP1 + c];
    for (int r = r0; r <= c; ++r)
        run += rb[(size_t)r * NP1 + c];
    dg[b * NP1 + c] = run;
}
// Column pass emitting Bsum directly (f32, upper triangle) + C0. Final Sp is
// never materialized. Bsum[r][c-1] = dg[c] + dg[r] - 2*Sp[r][c], r < c.
// s==0 blocks also emit row 0: Bsum[0][c-1] = dg[c].
__global__ __launch_bounds__(256)
void satc3_bsum(const double* __restrict__ R, const double* __restrict__ aux,
                const double* __restrict__ dg,
                float* __restrict__ Bsum, float* __restrict__ C0)
{
    const int b = blockIdx.z, s = blockIdx.y, cb = blockIdx.x;
    const int r0 = s * 256 + 1;
    if (r0 >= (cb + 1) * 256) return;          // no r < c possible in this tile
    const int c = cb * 256 + threadIdx.x;
    if (c > NTOK || c == 0) return;
    const double* rb = R + (size_t)b * ST2;
    const double* dgb = dg + b * NP1;
    const double dgc = dgb[c];
    float* Bb = Bsum + (size_t)b * NTOK * NTOK;
    float* C0b = C0 + b * NTOK;
    if (s == 0) {                               // row 0
        const float v0 = (float)dgc;
        Bb[c - 1] = v0;
        if (c == NTOK) C0b[0] = v0;
    }
    double run = aux[(size_t)(b * 8 + s) * NP1 + c];
    const int rend = r0 + 256;
    for (int r = r0; r < rend; ++r) {
        run += rb[(size_t)r * NP1 + c];
        if (r < c) {
            const float v = (float)(dgc + dgb[r] - 2.0 * run);
            Bb[(size_t)r * NTOK + (c - 1)] = v;
            if (c == NTOK) C0b[r] = v;
        }
    }
}

// ---------------------------------------------------------------------------
// DP v10 (fence-free, register body, dwordx4-sc1 cs fill).
// ---------------------------------------------------------------------------
#define DP_BX 128
#define DP_PAIRS 8
#define RBBIG 3.0e37f

__device__ inline void cstore(float* p, float v)
{
    __hip_atomic_store(p, v, __ATOMIC_RELAXED, __HIP_MEMORY_SCOPE_AGENT);
}

__device__ inline void wait_flags(const int* flagsb, int need)
{
    if (threadIdx.x < DP_BX) {
        const int* f = flagsb + threadIdx.x * 4;
        while (__hip_atomic_load(f, __ATOMIC_RELAXED, __HIP_MEMORY_SCOPE_AGENT) < need)
            __builtin_amdgcn_s_sleep(1);
    }
    __syncthreads();
}

__device__ inline void publish(int* myflag, int val)
{
    asm volatile("s_waitcnt vmcnt(0)" ::: "memory");
    __syncthreads();
    if (threadIdx.x == 0)
        __hip_atomic_store(myflag, val, __ATOMIC_RELAXED, __HIP_MEMORY_SCOPE_AGENT);
}

template<int NC>
__device__ inline void load_rb(const float* __restrict__ brow, int colbase, int lane,
                               float (&rb)[NC])
{
#pragma unroll
    for (int c = 0; c < NC; ++c) {
        const int col = colbase + lane + c * 64;
        rb[c] = (col < NTOK) ? brow[col] : RBBIG;
    }
}

template<int NC>
__device__ inline float pass1(const float (&rb)[NC], const float* __restrict__ cs,
                              int coff, int V, int lane)
{
    float mn = FLT_MAX;
#pragma unroll
    for (int c = 0; c < NC; ++c) {
        const int idx = lane + c * 64;
        if (idx < V) mn = fminf(mn, rb[c] + cs[coff + idx]);
    }
#pragma unroll
    for (int o = 32; o; o >>= 1) mn = fminf(mn, __shfl_xor(mn, o));
    return mn;
}

template<int NC>
__device__ inline void pass2(const float (&rb)[NC], const float* __restrict__ cs,
                             int coff, int V, float mn, int lane, float (&ac)[NC])
{
    float w[NC];
    float s = 0.0f;
#pragma unroll
    for (int c = 0; c < NC; ++c) {
        const int idx = lane + c * 64;
        float x = 0.0f;
        if (idx < V) x = __expf(mn - (rb[c] + cs[coff + idx]));
        w[c] = x;
        s += x;
    }
#pragma unroll
    for (int o = 32; o; o >>= 1) s += __shfl_xor(s, o);
    const float inv = 1.0f / s;
#pragma unroll
    for (int c = 0; c < NC; ++c) ac[c] = __builtin_fmaf(w[c], inv, ac[c]);
}

template<int NC>
__device__ inline void merge_acc(const float (&ac)[NC], int base, int lane,
                                 float* __restrict__ acc_lds)
{
#pragma unroll
    for (int c = 0; c < NC; ++c) {
        const int col = base + lane + c * 64;
        if (col < NTOK && ac[c] != 0.0f) atomicAdd(&acc_lds[col], ac[c]);
    }
}

__global__ __launch_bounds__(256, 1)
void dp_fused_kernel(const float* __restrict__ Bsum,
                     float* __restrict__ Ca, float* __restrict__ Cb,
                     float* __restrict__ tsum, int* __restrict__ flags)
{
    __shared__ float cs[NTOK];
    __shared__ float acc_lds[NTOK];
    const int b = blockIdx.y;
    const int t = threadIdx.x, lane = t & 63, wv = t >> 6;
    const float* Bb = Bsum + (size_t)b * NTOK * NTOK;
    const int pbase = blockIdx.x * DP_PAIRS;
    int* flagsb = flags + b * DP_BX * 4;
    int* myflag = flagsb + blockIdx.x * 4;

    const int p0 = pbase + wv * 2, p1 = p0 + 1;
    const int i1_0 = NTOK - 1 - p0, i1_1 = NTOK - 1 - p1;

    float rbA0[32], rbB0[16], rbA1[32], rbB1[16];
    load_rb<32>(Bb + (size_t)p0 * NTOK, p0, lane, rbA0);
    load_rb<16>(Bb + (size_t)i1_0 * NTOK, i1_0, lane, rbB0);
    load_rb<32>(Bb + (size_t)p1 * NTOK, p1, lane, rbA1);
    load_rb<16>(Bb + (size_t)i1_1 * NTOK, i1_1, lane, rbB1);

    float acA0[32] = {}, acB0[16] = {}, acA1[32] = {}, acB1[16] = {};

    for (int j = t; j < NTOK; j += 256) acc_lds[j] = 0.0f;

    // C0 (shifted): Csh[i-1] = Bsum[i][N-1]
    if (t < DP_PAIRS) {
        const int p = pbase + t, i1 = NTOK - 1 - p;
        if (p > 0) cstore(&Ca[b * NTOK + p - 1], Bb[(size_t)p * NTOK + NTOK - 1]);
        cstore(&Ca[b * NTOK + i1 - 1], Bb[(size_t)i1 * NTOK + NTOK - 1]);
    }
    publish(myflag, 0);

    const float* Cr = Ca;
    float* Cn = Cb;

    for (int k = 1; k < KSEG; ++k) {
        wait_flags(flagsb, k - 1);
        {
            const float* base  = Cr + b * NTOK + t * 4;
            const float* base2 = base + 1024;
            float4 va, vb;
            asm volatile(
                "global_load_dwordx4 %0, %2, off sc1\n\t"
                "global_load_dwordx4 %1, %3, off sc1\n\t"
                "s_waitcnt vmcnt(0)"
                : "=&v"(va), "=&v"(vb)
                : "v"(base), "v"(base2)
                : "memory");
            *(float4*)&cs[t * 4] = va;
            *(float4*)&cs[t * 4 + 1024] = vb;
        }
        __syncthreads();
        float* Cnb = Cn + b * NTOK;
        const int jmax = NTOK - k;

        const int VA0 = jmax - p0, VA1 = jmax - p1;
        const int VB0 = p0 + 1 - k, VB1 = p1 + 1 - k;
        const float mnA0 = pass1<32>(rbA0, cs, p0, VA0, lane);
        float mnB0 = 0.0f, mnB1 = 0.0f;
        if (p0 >= k) mnB0 = pass1<16>(rbB0, cs, i1_0, VB0, lane);
        const float mnA1 = pass1<32>(rbA1, cs, p1, VA1, lane);
        if (p1 >= k) mnB1 = pass1<16>(rbB1, cs, i1_1, VB1, lane);
        if (lane == 0) {
            if (p0 > 0) cstore(&Cnb[p0 - 1], mnA0);
            cstore(&Cnb[i1_0 - 1], (p0 >= k) ? mnB0 : 0.0f);
            cstore(&Cnb[p1 - 1], mnA1);
            cstore(&Cnb[i1_1 - 1], (p1 >= k) ? mnB1 : 0.0f);
        }
        publish(myflag, k);

        pass2<32>(rbA0, cs, p0, VA0, mnA0, lane, acA0);
        if (p0 >= k) pass2<16>(rbB0, cs, i1_0, VB0, mnB0, lane, acB0);
        pass2<32>(rbA1, cs, p1, VA1, mnA1, lane, acA1);
        if (p1 >= k) pass2<16>(rbB1, cs, i1_1, VB1, mnB1, lane, acB1);

        float* tmp = (float*)Cr; Cr = Cn; Cn = tmp;
    }

    __syncthreads();
    merge_acc<32>(acA0, p0, lane, acc_lds);
    merge_acc<16>(acB0, i1_0, lane, acc_lds);
    merge_acc<32>(acA1, p1, lane, acc_lds);
    merge_acc<16>(acB1, i1_1, lane, acc_lds);
    __syncthreads();
    float* ts = tsum + b * NTOK;
    for (int j = t; j < NTOK; j += 256) {
        const float v = acc_lds[j];
        if (v != 0.0f) atomicAdd(&ts[j], v);
    }
}

// ---- fallback path (29 launches) ----
__global__ __launch_bounds__(256)
void dp_step_kernel(const float* __restrict__ Bsum, const float* __restrict__ Cprev,
                    float* __restrict__ Cnext, float* __restrict__ tsum, int kk)
{
    __shared__ float cs[NTOK];
    __shared__ float acc[NTOK];
    const int b = blockIdx.y;
    const int t = threadIdx.x, lane = t & 63, wv = t >> 6;
    const float* Cp = Cprev + b * NTOK;
    for (int j = t; j < NTOK; j += 256) {
        cs[j] = (j < NTOK - 1) ? Cp[j + 1] : 0.0f;
        acc[j] = 0.0f;
    }
    __syncthreads();
    const int jmax = NTOK - kk;
    const int w = blockIdx.x * 4 + wv;
    const float* Bb = Bsum + (size_t)b * NTOK * NTOK;
    float* Cn = Cnext + b * NTOK;
    const int rows[4] = { w, 1023 - w, 1024 + w, 2047 - w };
#pragma unroll
    for (int rr = 0; rr < 4; ++rr) {
        const int i = rows[rr];
        if (i >= jmax) { if (lane == 0) Cn[i] = 0.0f; continue; }
        const float* brow = Bb + (size_t)i * NTOK;
        const int j0 = i + lane;
        float mv[32];
        float mn = FLT_MAX;
#pragma unroll
        for (int c = 0; c < 32; ++c) {
            const int j = j0 + c * 64;
            float v = FLT_MAX;
            if (j < jmax) v = brow[j] + cs[j];
            mv[c] = v;
            mn = fminf(mn, v);
        }
#pragma unroll
        for (int off = 32; off; off >>= 1) mn = fminf(mn, __shfl_xor(mn, off));
        if (lane == 0) Cn[i] = mn;
        float s = 0.0f;
#pragma unroll
        for (int c = 0; c < 32; ++c) {
            const int j = j0 + c * 64;
            float p = 0.0f;
            if (j < jmax) p = __expf(mn - mv[c]);
            mv[c] = p;
            s += p;
        }
#pragma unroll
        for (int off = 32; off; off >>= 1) s += __shfl_xor(s, off);
        const float inv = 1.0f / s;
#pragma unroll
        for (int c = 0; c < 32; ++c) {
            const int j = j0 + c * 64;
            if (j < jmax) atomicAdd(&acc[j], mv[c] * inv);
        }
    }
    __syncthreads();
    float* ts = tsum + b * NTOK;
    for (int j = t; j < NTOK; j += 256) {
        const float v = acc[j];
        if (v != 0.0f) atomicAdd(&ts[j], v);
    }
}

__global__ void finalize_kernel(const float* __restrict__ tsum, float* __restrict__ out)
{
    const int b = blockIdx.y;
    const int j = blockIdx.x * 256 + threadIdx.x;
    if (j >= NTOK) return;
    float ts = tsum[b * NTOK + j];
    int steps = NTOK - 1 - j;
    if (steps > KSEG - 1) steps = KSEG - 1;
    float tc = (float)(j + 1) * (float)steps;
    if (j == NTOK - 1) { ts += (float)NTOK; tc += (float)NTOK; }
    out[b * NTOK + j] = ts / tc;
}

extern "C" void kernel_launch(void* const* d_in, const int* in_sizes, int n_in,
                              void* d_out, int out_size, void* d_ws, size_t ws_size,
                              hipStream_t stream)
{
    const float* x  = (const float*)d_in[0];
    const float* W0 = (const float*)d_in[1];
    const float* b0 = (const float*)d_in[2];
    const float* W1 = (const float*)d_in[3];
    const float* b1 = (const float*)d_in[4];
    float* out = (float*)d_out;

    char* ws = (char*)d_ws;
    size_t off = 0;
    auto alloc = [&](size_t bytes) -> void* {
        void* p = (void*)(ws + off);
        off += (bytes + 255) & ~(size_t)255;
        return p;
    };
    double* Rsc  = (double*)alloc((size_t)BATCH * ST2 * sizeof(double));          // rowscan
    float*  Dm   = (float*) alloc((size_t)BATCH * NTOK * NTOK * sizeof(float));   // D / Bsum / l0 partials
    float*  h    = (float*) alloc((size_t)BATCH * NTOK * HDIM * sizeof(float));
    float*  e    = (float*) alloc((size_t)BATCH * NTOK * EDIM * sizeof(float));
    float*  dvec = (float*) alloc((size_t)BATCH * NTOK * sizeof(float));
    double* dg   = (double*)alloc((size_t)BATCH * NP1 * sizeof(double));
    double* aux  = (double*)alloc((size_t)BATCH * 8 * NP1 * sizeof(double));
    float*  CA   = (float*) alloc((size_t)BATCH * NTOK * sizeof(float));
    float*  CB   = (float*) alloc((size_t)BATCH * NTOK * sizeof(float));
    float*  tsum = (float*) alloc((size_t)BATCH * NTOK * sizeof(float));
    int*    flags= (int*)   alloc((size_t)BATCH * DP_BX * 4 * sizeof(int));
    (void)ws_size; (void)in_sizes; (void)n_in; (void)out_size;

    hipMemsetAsync(tsum, 0, (size_t)BATCH * NTOK * sizeof(float), stream);
    hipMemsetAsync(flags, 0xFF, (size_t)BATCH * DP_BX * 4 * sizeof(int), stream);

    // Layer 0 (split-K=2, partials in Dm region): h = relu(x @ W0^T + b0)
    float* Hpart = Dm;
    gemm_nt128s<<<dim3(HDIM / 128, (BATCH * NTOK) / 128, 2), 256, 0, stream>>>(
        x, FDIM, W0, FDIM, Hpart, HDIM, BATCH * NTOK, FDIM / 2);
    combine_relu<<<dim3((BATCH * NTOK * HDIM / 4) / 256), 256, 0, stream>>>(
        Hpart, Hpart + (size_t)BATCH * NTOK * HDIM, b0, h);
    // Layer 1: e = h @ W1^T + b1
    gemm_nt64<<<dim3(EDIM / 64, (BATCH * NTOK) / 64), 256, 0, stream>>>(
        h, HDIM, W1, HDIM, b1, e, EDIM, HDIM);
    rownorm_kernel<<<dim3((BATCH * NTOK) / 4), 256, 0, stream>>>(e, dvec);
    // D (full matrix) into Dm
    gemm_corr<<<dim3(NTOK / 128, NTOK / 128, BATCH), 256, 0, stream>>>(e, Dm, dvec);
    // SAT: rowscan -> strip sums -> strip prefix -> diag -> fused Bsum emit
    sat_row_kernel<<<dim3(NTOK, BATCH), 256, 0, stream>>>(Dm, Rsc);
    satc1<<<dim3((NP1 + 255) / 256, 8, BATCH), 256, 0, stream>>>(Rsc, aux);
    satc2<<<dim3((NP1 + 255) / 256, BATCH), 256, 0, stream>>>(aux);
    satc_diag<<<dim3((NP1 + 255) / 256, BATCH), 256, 0, stream>>>(Rsc, aux, dg);
    satc3_bsum<<<dim3((NP1 + 255) / 256, 8, BATCH), 256, 0, stream>>>(
        Rsc, aux, dg, Dm, CA);   // overwrites D upper triangle with Bsum

    // Fused DP
    void* args[] = { (void*)&Dm, (void*)&CA, (void*)&CB, (void*)&tsum, (void*)&flags };
    hipError_t err = hipLaunchCooperativeKernel((const void*)dp_fused_kernel,
                                                dim3(DP_BX, BATCH), dim3(256),
                                                args, 0, stream);
    if (err != hipSuccess) {
        float* cp = CA; float* cn = CB;
        for (int kk = 1; kk < KSEG; ++kk) {
            dp_step_kernel<<<dim3(128, BATCH), 256, 0, stream>>>(Dm, cp, cn, tsum, kk);
            float* tmp = cp; cp = cn; cn = tmp;
        }
    }
    finalize_kernel<<<dim3(NTOK / 256, BATCH), 256, 0, stream>>>(tsum, out);
}

// Round 16
// 636.017 us; speedup vs baseline: 1.2634x; 1.2634x over previous
//
#include <hip/hip_runtime.h>
#include <hip/hip_bf16.h>
#include <float.h>

// Problem constants (OSG_C_29987461660961)
#define NTOK 2048
#define FDIM 1024
#define HDIM 512
#define EDIM 256
#define BATCH 2
#define KSEG 30
#define NP1 2049
#define STRIPS 32
#define SROWS 64
static const size_t ST2 = (size_t)NP1 * NP1;   // rowscan per-batch element count

// ---------------------------------------------------------------------------
// NT GEMM (64x64 tile, 4x4 micro) — layer 1
// ---------------------------------------------------------------------------
__global__ __launch_bounds__(256)
void gemm_nt64(const float* __restrict__ A, int lda,
               const float* __restrict__ Bm, int ldb,
               const float* __restrict__ bias,
               float* __restrict__ C, int ldc, int K)
{
    __shared__ float As[32][68];
    __shared__ float Bs[32][68];
    const int t = threadIdx.x;
    const int tx = t & 15, ty = t >> 4;
    const int lrow = t >> 3, lkv = t & 7;
    const int by = blockIdx.y, bx = blockIdx.x;

    float acc[4][4] = {};
    const int ktiles = K >> 5;
    for (int kt = 0; kt < ktiles; ++kt) {
#pragma unroll
        for (int h = 0; h < 2; ++h) {
            const int r = lrow + h * 32;
            const float4 av = *(const float4*)(A + (size_t)(by * 64 + r) * lda + kt * 32 + lkv * 4);
            As[lkv * 4 + 0][r] = av.x; As[lkv * 4 + 1][r] = av.y;
            As[lkv * 4 + 2][r] = av.z; As[lkv * 4 + 3][r] = av.w;
            const float4 bv = *(const float4*)(Bm + (size_t)(bx * 64 + r) * ldb + kt * 32 + lkv * 4);
            Bs[lkv * 4 + 0][r] = bv.x; Bs[lkv * 4 + 1][r] = bv.y;
            Bs[lkv * 4 + 2][r] = bv.z; Bs[lkv * 4 + 3][r] = bv.w;
        }
        __syncthreads();
#pragma unroll
        for (int kk = 0; kk < 32; ++kk) {
            const float4 a = *(const float4*)&As[kk][ty * 4];
            const float4 b = *(const float4*)&Bs[kk][tx * 4];
            const float ar[4] = {a.x, a.y, a.z, a.w};
            const float br[4] = {b.x, b.y, b.z, b.w};
#pragma unroll
            for (int i = 0; i < 4; ++i)
#pragma unroll
                for (int j = 0; j < 4; ++j)
                    acc[i][j] = fmaf(ar[i], br[j], acc[i][j]);
        }
        __syncthreads();
    }

    const int row0 = by * 64 + ty * 4;
    const int col0 = bx * 64 + tx * 4;
#pragma unroll
    for (int i = 0; i < 4; ++i) {
        float4 v4;
        v4.x = acc[i][0] + bias[col0 + 0];
        v4.y = acc[i][1] + bias[col0 + 1];
        v4.z = acc[i][2] + bias[col0 + 2];
        v4.w = acc[i][3] + bias[col0 + 3];
        *(float4*)(C + (size_t)(row0 + i) * ldc + col0) = v4;
    }
}

// ---------------------------------------------------------------------------
// Split-K 128x128 / 8x8 GEMM partial for layer 0 (x @ W0^T).
// ---------------------------------------------------------------------------
__global__ __launch_bounds__(256)
void gemm_nt128s(const float* __restrict__ A, int lda,
                 const float* __restrict__ Bm, int ldb,
                 float* __restrict__ Cp, int ldc, int M, int khalf)
{
    __shared__ float As[16][140];
    __shared__ float Bs[16][140];
    const int t = threadIdx.x;
    const int tx = t & 15, ty = t >> 4;
    const int by = blockIdx.y, bx = blockIdx.x;
    const int k0 = blockIdx.z * khalf;
    const int fq = t & 3, lr = t >> 2;

    float acc[8][8] = {};
    for (int kt = 0; kt < khalf / 16; ++kt) {
#pragma unroll
        for (int h = 0; h < 2; ++h) {
            const int r = lr + h * 64;
            const int rr = r + 4 * (r >> 5);
            const float4 av = *(const float4*)(A + (size_t)(by * 128 + r) * lda + k0 + kt * 16 + fq * 4);
            As[fq * 4 + 0][rr] = av.x; As[fq * 4 + 1][rr] = av.y;
            As[fq * 4 + 2][rr] = av.z; As[fq * 4 + 3][rr] = av.w;
            const float4 bv = *(const float4*)(Bm + (size_t)(bx * 128 + r) * ldb + k0 + kt * 16 + fq * 4);
            Bs[fq * 4 + 0][rr] = bv.x; Bs[fq * 4 + 1][rr] = bv.y;
            Bs[fq * 4 + 2][rr] = bv.z; Bs[fq * 4 + 3][rr] = bv.w;
        }
        __syncthreads();
        const int ma = 8 * ty + 4 * (ty >> 2);
        const int mb = 8 * tx + 4 * (tx >> 2);
#pragma unroll
        for (int k = 0; k < 16; ++k) {
            const float4 a0 = *(const float4*)&As[k][ma];
            const float4 a1 = *(const float4*)&As[k][ma + 4];
            const float4 b0 = *(const float4*)&Bs[k][mb];
            const float4 b1 = *(const float4*)&Bs[k][mb + 4];
            const float ar[8] = {a0.x, a0.y, a0.z, a0.w, a1.x, a1.y, a1.z, a1.w};
            const float br[8] = {b0.x, b0.y, b0.z, b0.w, b1.x, b1.y, b1.z, b1.w};
#pragma unroll
            for (int i = 0; i < 8; ++i)
#pragma unroll
                for (int j = 0; j < 8; ++j)
                    acc[i][j] = fmaf(ar[i], br[j], acc[i][j]);
        }
        __syncthreads();
    }

    float* outp = Cp + (size_t)blockIdx.z * M * ldc;
    const int row0 = by * 128 + ty * 8;
    const int col0 = bx * 128 + tx * 8;
#pragma unroll
    for (int i = 0; i < 8; ++i) {
        float4 w0; w0.x = acc[i][0]; w0.y = acc[i][1]; w0.z = acc[i][2]; w0.w = acc[i][3];
        float4 w1; w1.x = acc[i][4]; w1.y = acc[i][5]; w1.z = acc[i][6]; w1.w = acc[i][7];
        *(float4*)(outp + (size_t)(row0 + i) * ldc + col0) = w0;
        *(float4*)(outp + (size_t)(row0 + i) * ldc + col0 + 4) = w1;
    }
}

// h = relu(p0 + p1 + bias)
__global__ __launch_bounds__(256)
void combine_relu(const float* __restrict__ p0, const float* __restrict__ p1,
                  const float* __restrict__ bias, float* __restrict__ hout)
{
    const int idx = blockIdx.x * 256 + threadIdx.x;
    const float4 a = ((const float4*)p0)[idx];
    const float4 b = ((const float4*)p1)[idx];
    const float4 bs = *(const float4*)&bias[(idx & 127) * 4];
    float4 o;
    o.x = fmaxf(a.x + b.x + bs.x, 0.0f);
    o.y = fmaxf(a.y + b.y + bs.y, 0.0f);
    o.z = fmaxf(a.z + b.z + bs.z, 0.0f);
    o.w = fmaxf(a.w + b.w + bs.w, 0.0f);
    ((float4*)hout)[idx] = o;
}

// ---------------------------------------------------------------------------
// Correlation GEMM + D epilogue: 128x128 tile, BK=16, 8x8 microtile.
// ---------------------------------------------------------------------------
__global__ __launch_bounds__(256)
void gemm_corr(const float* __restrict__ E, float* __restrict__ D,
               const float* __restrict__ dvec)
{
    __shared__ float As[16][140];
    __shared__ float Bs[16][140];
    const int z = blockIdx.z;
    const float* Eb = E + (size_t)z * NTOK * EDIM;
    float* Db = D + (size_t)z * NTOK * NTOK;
    const int t = threadIdx.x;
    const int tx = t & 15, ty = t >> 4;
    const int by = blockIdx.y, bx = blockIdx.x;
    const int fq = t & 3, lr = t >> 2;

    float acc[8][8] = {};
    for (int kt = 0; kt < EDIM / 16; ++kt) {
#pragma unroll
        for (int h = 0; h < 2; ++h) {
            const int r = lr + h * 64;
            const int rr = r + 4 * (r >> 5);
            const float4 av = *(const float4*)(Eb + (size_t)(by * 128 + r) * EDIM + kt * 16 + fq * 4);
            As[fq * 4 + 0][rr] = av.x; As[fq * 4 + 1][rr] = av.y;
            As[fq * 4 + 2][rr] = av.z; As[fq * 4 + 3][rr] = av.w;
            const float4 bv = *(const float4*)(Eb + (size_t)(bx * 128 + r) * EDIM + kt * 16 + fq * 4);
            Bs[fq * 4 + 0][rr] = bv.x; Bs[fq * 4 + 1][rr] = bv.y;
            Bs[fq * 4 + 2][rr] = bv.z; Bs[fq * 4 + 3][rr] = bv.w;
        }
        __syncthreads();
        const int ma = 8 * ty + 4 * (ty >> 2);
        const int mb = 8 * tx + 4 * (tx >> 2);
#pragma unroll
        for (int k = 0; k < 16; ++k) {
            const float4 a0 = *(const float4*)&As[k][ma];
            const float4 a1 = *(const float4*)&As[k][ma + 4];
            const float4 b0 = *(const float4*)&Bs[k][mb];
            const float4 b1 = *(const float4*)&Bs[k][mb + 4];
            const float ar[8] = {a0.x, a0.y, a0.z, a0.w, a1.x, a1.y, a1.z, a1.w};
            const float br[8] = {b0.x, b0.y, b0.z, b0.w, b1.x, b1.y, b1.z, b1.w};
#pragma unroll
            for (int i = 0; i < 8; ++i)
#pragma unroll
                for (int j = 0; j < 8; ++j)
                    acc[i][j] = fmaf(ar[i], br[j], acc[i][j]);
        }
        __syncthreads();
    }

    const int row0 = by * 128 + ty * 8;
    const int col0 = bx * 128 + tx * 8;
    float di[8], dj[8];
#pragma unroll
    for (int i = 0; i < 8; ++i) di[i] = dvec[z * NTOK + row0 + i];
#pragma unroll
    for (int j = 0; j < 8; ++j) dj[j] = dvec[z * NTOK + col0 + j];
#pragma unroll
    for (int i = 0; i < 8; ++i) {
        float o[8];
#pragma unroll
        for (int j = 0; j < 8; ++j) {
            const float den = sqrtf(fmaxf(di[i] * dj[j], 1e-8f));
            o[j] = 0.5f * (1.0f - acc[i][j] / den);
        }
        float4 w0; w0.x = o[0]; w0.y = o[1]; w0.z = o[2]; w0.w = o[3];
        float4 w1; w1.x = o[4]; w1.y = o[5]; w1.z = o[6]; w1.w = o[7];
        *(float4*)(Db + (size_t)(row0 + i) * NTOK + col0) = w0;
        *(float4*)(Db + (size_t)(row0 + i) * NTOK + col0 + 4) = w1;
    }
}

__global__ __launch_bounds__(256)
void rownorm_kernel(const float* __restrict__ e, float* __restrict__ dvec)
{
    const int wid = (blockIdx.x * 256 + threadIdx.x) >> 6;
    const int lane = threadIdx.x & 63;
    if (wid >= BATCH * NTOK) return;
    const float4 v = *(const float4*)(e + (size_t)wid * EDIM + lane * 4);
    float s = v.x * v.x + v.y * v.y + v.z * v.z + v.w * v.w;
#pragma unroll
    for (int off = 32; off; off >>= 1) s += __shfl_xor(s, off);
    if (lane == 0) dvec[wid] = s;
}

// Row-wise inclusive scan of D (f32) into R rows 1..N (f64). R[r][0]=0.
__global__ __launch_bounds__(256)
void sat_row_kernel(const float* __restrict__ D, double* __restrict__ R)
{
    const int b = blockIdx.y;
    const int r = blockIdx.x + 1;
    const float* drow = D + (size_t)b * NTOK * NTOK + (size_t)(r - 1) * NTOK;
    double* rrow = R + (size_t)b * ST2 + (size_t)r * NP1;
    const int t = threadIdx.x, lane = t & 63, wv = t >> 6;
    __shared__ double wtot[4];
    double carry = 0.0;
    if (t == 0) rrow[0] = 0.0;
    for (int ch = 0; ch < NTOK / 256; ++ch) {
        double v = (double)drow[ch * 256 + t];
#pragma unroll
        for (int d = 1; d < 64; d <<= 1) {
            const double u = __shfl_up(v, (unsigned)d, 64);
            if (lane >= d) v += u;
        }
        if (lane == 63) wtot[wv] = v;
        __syncthreads();
        double pre = carry;
        for (int ww = 0; ww < wv; ++ww) pre += wtot[ww];
        const double tot = carry + wtot[0] + wtot[1] + wtot[2] + wtot[3];
        rrow[ch * 256 + t + 1] = v + pre;
        __syncthreads();
        carry = tot;
    }
}

// strip sums: aux[s][c] = sum_{r in strip s} R[r][c]   (strips of 64 rows)
__global__ void satc1(const double* __restrict__ R, double* __restrict__ aux)
{
    const int b = blockIdx.z, s = blockIdx.y, cb = blockIdx.x;
    if ((cb + 1) * 256 <= s * SROWS) return;   // aux[s][c] only used when c > s*64
    const int c = cb * 256 + threadIdx.x;
    if (c > NTOK) return;
    const double* rb = R + (size_t)b * ST2;
    double tt = 0.0;
    const int r0 = s * SROWS + 1;
    for (int r = r0; r < r0 + SROWS; ++r) tt += rb[(size_t)r * NP1 + c];
    aux[(size_t)(b * STRIPS + s) * NP1 + c] = tt;
}
// exclusive prefix over strips
__global__ void satc2(double* __restrict__ aux)
{
    const int b = blockIdx.y;
    const int c = blockIdx.x * 256 + threadIdx.x;
    if (c > NTOK) return;
    double run = 0.0;
    for (int s = 0; s < STRIPS; ++s) {
        const size_t id = (size_t)(b * STRIPS + s) * NP1 + c;
        const double tt = aux[id]; aux[id] = run; run += tt;
    }
}
// dg[c] = final colsum Sp[c][c] = aux[strip(c)][c] + partial rows within strip
__global__ void satc_diag(const double* __restrict__ R, const double* __restrict__ aux,
                          double* __restrict__ dg)
{
    const int b = blockIdx.y;
    const int c = blockIdx.x * 256 + threadIdx.x;
    if (c > NTOK) return;
    if (c == 0) { dg[b * NP1] = 0.0; return; }
    const int s = (c - 1) / SROWS;
    const int r0 = s * SROWS + 1;
    const double* rb = R + (size_t)b * ST2;
    double run = aux[(size_t)(b * STRIPS + s) * NP1 + c];
    for (int r = r0; r <= c; ++r)
        run += rb[(size_t)r * NP1 + c];
    dg[b * NP1 + c] = run;
}
// Column pass emitting Bsum directly (f32, upper triangle) + C0.
// Bsum[r][c-1] = dg[c] + dg[r] - 2*Sp[r][c], r < c; row 0: Bsum[0][c-1]=dg[c].
__global__ __launch_bounds__(256)
void satc3_bsum(const double* __restrict__ R, const double* __restrict__ aux,
                const double* __restrict__ dg,
                float* __restrict__ Bsum, float* __restrict__ C0)
{
    const int b = blockIdx.z, s = blockIdx.y, cb = blockIdx.x;
    const int r0 = s * SROWS + 1;
    if (r0 >= (cb + 1) * 256) return;          // no r < c possible in this tile
    const int c = cb * 256 + threadIdx.x;
    if (c > NTOK || c == 0) return;
    const double* rb = R + (size_t)b * ST2;
    const double* dgb = dg + b * NP1;
    const double dgc = dgb[c];
    float* Bb = Bsum + (size_t)b * NTOK * NTOK;
    float* C0b = C0 + b * NTOK;
    if (s == 0) {                               // row 0
        const float v0 = (float)dgc;
        Bb[c - 1] = v0;
        if (c == NTOK) C0b[0] = v0;
    }
    double run = aux[(size_t)(b * STRIPS + s) * NP1 + c];
    const int rend = r0 + SROWS;
    for (int r = r0; r < rend; ++r) {
        run += rb[(size_t)r * NP1 + c];
        if (r < c) {
            const float v = (float)(dgc + dgb[r] - 2.0 * run);
            Bb[(size_t)r * NTOK + (c - 1)] = v;
            if (c == NTOK) C0b[r] = v;
        }
    }
}

// ---------------------------------------------------------------------------
// DP v10 (fence-free, register body, dwordx4-sc1 cs fill).
// ---------------------------------------------------------------------------
#define DP_BX 128
#define DP_PAIRS 8
#define RBBIG 3.0e37f

__device__ inline void cstore(float* p, float v)
{
    __hip_atomic_store(p, v, __ATOMIC_RELAXED, __HIP_MEMORY_SCOPE_AGENT);
}

__device__ inline void wait_flags(const int* flagsb, int need)
{
    if (threadIdx.x < DP_BX) {
        const int* f = flagsb + threadIdx.x * 4;
        while (__hip_atomic_load(f, __ATOMIC_RELAXED, __HIP_MEMORY_SCOPE_AGENT) < need)
            __builtin_amdgcn_s_sleep(1);
    }
    __syncthreads();
}

__device__ inline void publish(int* myflag, int val)
{
    asm volatile("s_waitcnt vmcnt(0)" ::: "memory");
    __syncthreads();
    if (threadIdx.x == 0)
        __hip_atomic_store(myflag, val, __ATOMIC_RELAXED, __HIP_MEMORY_SCOPE_AGENT);
}

template<int NC>
__device__ inline void load_rb(const float* __restrict__ brow, int colbase, int lane,
                               float (&rb)[NC])
{
#pragma unroll
    for (int c = 0; c < NC; ++c) {
        const int col = colbase + lane + c * 64;
        rb[c] = (col < NTOK) ? brow[col] : RBBIG;
    }
}

template<int NC>
__device__ inline float pass1(const float (&rb)[NC], const float* __restrict__ cs,
                              int coff, int V, int lane)
{
    float mn = FLT_MAX;
#pragma unroll
    for (int c = 0; c < NC; ++c) {
        const int idx = lane + c * 64;
        if (idx < V) mn = fminf(mn, rb[c] + cs[coff + idx]);
    }
#pragma unroll
    for (int o = 32; o; o >>= 1) mn = fminf(mn, __shfl_xor(mn, o));
    return mn;
}

template<int NC>
__device__ inline void pass2(const float (&rb)[NC], const float* __restrict__ cs,
                             int coff, int V, float mn, int lane, float (&ac)[NC])
{
    float w[NC];
    float s = 0.0f;
#pragma unroll
    for (int c = 0; c < NC; ++c) {
        const int idx = lane + c * 64;
        float x = 0.0f;
        if (idx < V) x = __expf(mn - (rb[c] + cs[coff + idx]));
        w[c] = x;
        s += x;
    }
#pragma unroll
    for (int o = 32; o; o >>= 1) s += __shfl_xor(s, o);
    const float inv = 1.0f / s;
#pragma unroll
    for (int c = 0; c < NC; ++c) ac[c] = __builtin_fmaf(w[c], inv, ac[c]);
}

template<int NC>
__device__ inline void merge_acc(const float (&ac)[NC], int base, int lane,
                                 float* __restrict__ acc_lds)
{
#pragma unroll
    for (int c = 0; c < NC; ++c) {
        const int col = base + lane + c * 64;
        if (col < NTOK && ac[c] != 0.0f) atomicAdd(&acc_lds[col], ac[c]);
    }
}

__global__ __launch_bounds__(256, 1)
void dp_fused_kernel(const float* __restrict__ Bsum,
                     float* __restrict__ Ca, float* __restrict__ Cb,
                     float* __restrict__ tsum, int* __restrict__ flags)
{
    __shared__ float cs[NTOK];
    __shared__ float acc_lds[NTOK];
    const int b = blockIdx.y;
    const int t = threadIdx.x, lane = t & 63, wv = t >> 6;
    const float* Bb = Bsum + (size_t)b * NTOK * NTOK;
    const int pbase = blockIdx.x * DP_PAIRS;
    int* flagsb = flags + b * DP_BX * 4;
    int* myflag = flagsb + blockIdx.x * 4;

    const int p0 = pbase + wv * 2, p1 = p0 + 1;
    const int i1_0 = NTOK - 1 - p0, i1_1 = NTOK - 1 - p1;

    float rbA0[32], rbB0[16], rbA1[32], rbB1[16];
    load_rb<32>(Bb + (size_t)p0 * NTOK, p0, lane, rbA0);
    load_rb<16>(Bb + (size_t)i1_0 * NTOK, i1_0, lane, rbB0);
    load_rb<32>(Bb + (size_t)p1 * NTOK, p1, lane, rbA1);
    load_rb<16>(Bb + (size_t)i1_1 * NTOK, i1_1, lane, rbB1);

    float acA0[32] = {}, acB0[16] = {}, acA1[32] = {}, acB1[16] = {};

    for (int j = t; j < NTOK; j += 256) acc_lds[j] = 0.0f;

    // C0 (shifted): Csh[i-1] = Bsum[i][N-1]
    if (t < DP_PAIRS) {
        const int p = pbase + t, i1 = NTOK - 1 - p;
        if (p > 0) cstore(&Ca[b * NTOK + p - 1], Bb[(size_t)p * NTOK + NTOK - 1]);
        cstore(&Ca[b * NTOK + i1 - 1], Bb[(size_t)i1 * NTOK + NTOK - 1]);
    }
    publish(myflag, 0);

    const float* Cr = Ca;
    float* Cn = Cb;

    for (int k = 1; k < KSEG; ++k) {
        wait_flags(flagsb, k - 1);
        {
            const float* base  = Cr + b * NTOK + t * 4;
            const float* base2 = base + 1024;
            float4 va, vb;
            asm volatile(
                "global_load_dwordx4 %0, %2, off sc1\n\t"
                "global_load_dwordx4 %1, %3, off sc1\n\t"
                "s_waitcnt vmcnt(0)"
                : "=&v"(va), "=&v"(vb)
                : "v"(base), "v"(base2)
                : "memory");
            *(float4*)&cs[t * 4] = va;
            *(float4*)&cs[t * 4 + 1024] = vb;
        }
        __syncthreads();
        float* Cnb = Cn + b * NTOK;
        const int jmax = NTOK - k;

        const int VA0 = jmax - p0, VA1 = jmax - p1;
        const int VB0 = p0 + 1 - k, VB1 = p1 + 1 - k;
        const float mnA0 = pass1<32>(rbA0, cs, p0, VA0, lane);
        float mnB0 = 0.0f, mnB1 = 0.0f;
        if (p0 >= k) mnB0 = pass1<16>(rbB0, cs, i1_0, VB0, lane);
        const float mnA1 = pass1<32>(rbA1, cs, p1, VA1, lane);
        if (p1 >= k) mnB1 = pass1<16>(rbB1, cs, i1_1, VB1, lane);
        if (lane == 0) {
            if (p0 > 0) cstore(&Cnb[p0 - 1], mnA0);
            cstore(&Cnb[i1_0 - 1], (p0 >= k) ? mnB0 : 0.0f);
            cstore(&Cnb[p1 - 1], mnA1);
            cstore(&Cnb[i1_1 - 1], (p1 >= k) ? mnB1 : 0.0f);
        }
        publish(myflag, k);

        pass2<32>(rbA0, cs, p0, VA0, mnA0, lane, acA0);
        if (p0 >= k) pass2<16>(rbB0, cs, i1_0, VB0, mnB0, lane, acB0);
        pass2<32>(rbA1, cs, p1, VA1, mnA1, lane, acA1);
        if (p1 >= k) pass2<16>(rbB1, cs, i1_1, VB1, mnB1, lane, acB1);

        float* tmp = (float*)Cr; Cr = Cn; Cn = tmp;
    }

    __syncthreads();
    merge_acc<32>(acA0, p0, lane, acc_lds);
    merge_acc<16>(acB0, i1_0, lane, acc_lds);
    merge_acc<32>(acA1, p1, lane, acc_lds);
    merge_acc<16>(acB1, i1_1, lane, acc_lds);
    __syncthreads();
    float* ts = tsum + b * NTOK;
    for (int j = t; j < NTOK; j += 256) {
        const float v = acc_lds[j];
        if (v != 0.0f) atomicAdd(&ts[j], v);
    }
}

// ---- fallback path (29 launches) ----
__global__ __launch_bounds__(256)
void dp_step_kernel(const float* __restrict__ Bsum, const float* __restrict__ Cprev,
                    float* __restrict__ Cnext, float* __restrict__ tsum, int kk)
{
    __shared__ float cs[NTOK];
    __shared__ float acc[NTOK];
    const int b = blockIdx.y;
    const int t = threadIdx.x, lane = t & 63, wv = t >> 6;
    const float* Cp = Cprev + b * NTOK;
    for (int j = t; j < NTOK; j += 256) {
        cs[j] = (j < NTOK - 1) ? Cp[j + 1] : 0.0f;
        acc[j] = 0.0f;
    }
    __syncthreads();
    const int jmax = NTOK - kk;
    const int w = blockIdx.x * 4 + wv;
    const float* Bb = Bsum + (size_t)b * NTOK * NTOK;
    float* Cn = Cnext + b * NTOK;
    const int rows[4] = { w, 1023 - w, 1024 + w, 2047 - w };
#pragma unroll
    for (int rr = 0; rr < 4; ++rr) {
        const int i = rows[rr];
        if (i >= jmax) { if (lane == 0) Cn[i] = 0.0f; continue; }
        const float* brow = Bb + (size_t)i * NTOK;
        const int j0 = i + lane;
        float mv[32];
        float mn = FLT_MAX;
#pragma unroll
        for (int c = 0; c < 32; ++c) {
            const int j = j0 + c * 64;
            float v = FLT_MAX;
            if (j < jmax) v = brow[j] + cs[j];
            mv[c] = v;
            mn = fminf(mn, v);
        }
#pragma unroll
        for (int off = 32; off; off >>= 1) mn = fminf(mn, __shfl_xor(mn, off));
        if (lane == 0) Cn[i] = mn;
        float s = 0.0f;
#pragma unroll
        for (int c = 0; c < 32; ++c) {
            const int j = j0 + c * 64;
            float p = 0.0f;
            if (j < jmax) p = __expf(mn - mv[c]);
            mv[c] = p;
            s += p;
        }
#pragma unroll
        for (int off = 32; off; off >>= 1) s += __shfl_xor(s, off);
        const float inv = 1.0f / s;
#pragma unroll
        for (int c = 0; c < 32; ++c) {
            const int j = j0 + c * 64;
            if (j < jmax) atomicAdd(&acc[j], mv[c] * inv);
        }
    }
    __syncthreads();
    float* ts = tsum + b * NTOK;
    for (int j = t; j < NTOK; j += 256) {
        const float v = acc[j];
        if (v != 0.0f) atomicAdd(&ts[j], v);
    }
}

__global__ void finalize_kernel(const float* __restrict__ tsum, float* __restrict__ out)
{
    const int b = blockIdx.y;
    const int j = blockIdx.x * 256 + threadIdx.x;
    if (j >= NTOK) return;
    float ts = tsum[b * NTOK + j];
    int steps = NTOK - 1 - j;
    if (steps > KSEG - 1) steps = KSEG - 1;
    float tc = (float)(j + 1) * (float)steps;
    if (j == NTOK - 1) { ts += (float)NTOK; tc += (float)NTOK; }
    out[b * NTOK + j] = ts / tc;
}

extern "C" void kernel_launch(void* const* d_in, const int* in_sizes, int n_in,
                              void* d_out, int out_size, void* d_ws, size_t ws_size,
                              hipStream_t stream)
{
    const float* x  = (const float*)d_in[0];
    const float* W0 = (const float*)d_in[1];
    const float* b0 = (const float*)d_in[2];
    const float* W1 = (const float*)d_in[3];
    const float* b1 = (const float*)d_in[4];
    float* out = (float*)d_out;

    char* ws = (char*)d_ws;
    size_t off = 0;
    auto alloc = [&](size_t bytes) -> void* {
        void* p = (void*)(ws + off);
        off += (bytes + 255) & ~(size_t)255;
        return p;
    };
    double* Rsc  = (double*)alloc((size_t)BATCH * ST2 * sizeof(double));          // rowscan
    float*  Dm   = (float*) alloc((size_t)BATCH * NTOK * NTOK * sizeof(float));   // D / Bsum / l0 partials
    float*  h    = (float*) alloc((size_t)BATCH * NTOK * HDIM * sizeof(float));
    float*  e    = (float*) alloc((size_t)BATCH * NTOK * EDIM * sizeof(float));
    float*  dvec = (float*) alloc((size_t)BATCH * NTOK * sizeof(float));
    double* dg   = (double*)alloc((size_t)BATCH * NP1 * sizeof(double));
    double* aux  = (double*)alloc((size_t)BATCH * STRIPS * NP1 * sizeof(double));
    float*  CA   = (float*) alloc((size_t)BATCH * NTOK * sizeof(float));
    float*  CB   = (float*) alloc((size_t)BATCH * NTOK * sizeof(float));
    float*  tsum = (float*) alloc((size_t)BATCH * NTOK * sizeof(float));
    int*    flags= (int*)   alloc((size_t)BATCH * DP_BX * 4 * sizeof(int));
    (void)ws_size; (void)in_sizes; (void)n_in; (void)out_size;

    hipMemsetAsync(tsum, 0, (size_t)BATCH * NTOK * sizeof(float), stream);
    hipMemsetAsync(flags, 0xFF, (size_t)BATCH * DP_BX * 4 * sizeof(int), stream);

    // Layer 0 (split-K=2, partials in Dm region): h = relu(x @ W0^T + b0)
    float* Hpart = Dm;
    gemm_nt128s<<<dim3(HDIM / 128, (BATCH * NTOK) / 128, 2), 256, 0, stream>>>(
        x, FDIM, W0, FDIM, Hpart, HDIM, BATCH * NTOK, FDIM / 2);
    combine_relu<<<dim3((BATCH * NTOK * HDIM / 4) / 256), 256, 0, stream>>>(
        Hpart, Hpart + (size_t)BATCH * NTOK * HDIM, b0, h);
    // Layer 1: e = h @ W1^T + b1
    gemm_nt64<<<dim3(EDIM / 64, (BATCH * NTOK) / 64), 256, 0, stream>>>(
        h, HDIM, W1, HDIM, b1, e, EDIM, HDIM);
    rownorm_kernel<<<dim3((BATCH * NTOK) / 4), 256, 0, stream>>>(e, dvec);
    // D (full matrix) into Dm
    gemm_corr<<<dim3(NTOK / 128, NTOK / 128, BATCH), 256, 0, stream>>>(e, Dm, dvec);
    // SAT: rowscan -> strip sums (64-row strips) -> prefix -> diag -> fused Bsum
    sat_row_kernel<<<dim3(NTOK, BATCH), 256, 0, stream>>>(Dm, Rsc);
    satc1<<<dim3((NP1 + 255) / 256, STRIPS, BATCH), 256, 0, stream>>>(Rsc, aux);
    satc2<<<dim3((NP1 + 255) / 256, BATCH), 256, 0, stream>>>(aux);
    satc_diag<<<dim3((NP1 + 255) / 256, BATCH), 256, 0, stream>>>(Rsc, aux, dg);
    satc3_bsum<<<dim3((NP1 + 255) / 256, STRIPS, BATCH), 256, 0, stream>>>(
        Rsc, aux, dg, Dm, CA);   // overwrites D upper triangle with Bsum

    // Fused DP
    void* args[] = { (void*)&Dm, (void*)&CA, (void*)&CB, (void*)&tsum, (void*)&flags };
    hipError_t err = hipLaunchCooperativeKernel((const void*)dp_fused_kernel,
                                                dim3(DP_BX, BATCH), dim3(256),
                                                args, 0, stream);
    if (err != hipSuccess) {
        float* cp = CA; float* cn = CB;
        for (int kk = 1; kk < KSEG; ++kk) {
            dp_step_kernel<<<dim3(128, BATCH), 256, 0, stream>>>(Dm, cp, cn, tsum, kk);
            float* tmp = cp; cp = cn; cn = tmp;
        }
    }
    finalize_kernel<<<dim3(NTOK / 256, BATCH), 256, 0, stream>>>(tsum, out);
}

// Round 17
// 629.050 us; speedup vs baseline: 1.2774x; 1.0111x over previous
//
#include <hip/hip_runtime.h>
#include <hip/hip_bf16.h>
#include <float.h>

// Problem constants (OSG_C_29987461660961)
#define NTOK 2048
#define FDIM 1024
#define HDIM 512
#define EDIM 256
#define BATCH 2
#define KSEG 30
#define NP1 2049
#define STRIPS 32
#define SROWS 64
static const size_t ST2 = (size_t)NP1 * NP1;   // rowscan per-batch element count

// ---------------------------------------------------------------------------
// Split-K 128x128 / 8x8 GEMM partial (shared by layer 0 and layer 1).
// grid (N/128, M/128, SPLITS); partial s at Cp + s*M*ldc.
// ---------------------------------------------------------------------------
__global__ __launch_bounds__(256)
void gemm_nt128s(const float* __restrict__ A, int lda,
                 const float* __restrict__ Bm, int ldb,
                 float* __restrict__ Cp, int ldc, int M, int ksplit)
{
    __shared__ float As[16][140];
    __shared__ float Bs[16][140];
    const int t = threadIdx.x;
    const int tx = t & 15, ty = t >> 4;
    const int by = blockIdx.y, bx = blockIdx.x;
    const int k0 = blockIdx.z * ksplit;
    const int fq = t & 3, lr = t >> 2;

    float acc[8][8] = {};
    for (int kt = 0; kt < ksplit / 16; ++kt) {
#pragma unroll
        for (int h = 0; h < 2; ++h) {
            const int r = lr + h * 64;
            const int rr = r + 4 * (r >> 5);
            const float4 av = *(const float4*)(A + (size_t)(by * 128 + r) * lda + k0 + kt * 16 + fq * 4);
            As[fq * 4 + 0][rr] = av.x; As[fq * 4 + 1][rr] = av.y;
            As[fq * 4 + 2][rr] = av.z; As[fq * 4 + 3][rr] = av.w;
            const float4 bv = *(const float4*)(Bm + (size_t)(bx * 128 + r) * ldb + k0 + kt * 16 + fq * 4);
            Bs[fq * 4 + 0][rr] = bv.x; Bs[fq * 4 + 1][rr] = bv.y;
            Bs[fq * 4 + 2][rr] = bv.z; Bs[fq * 4 + 3][rr] = bv.w;
        }
        __syncthreads();
        const int ma = 8 * ty + 4 * (ty >> 2);
        const int mb = 8 * tx + 4 * (tx >> 2);
#pragma unroll
        for (int k = 0; k < 16; ++k) {
            const float4 a0 = *(const float4*)&As[k][ma];
            const float4 a1 = *(const float4*)&As[k][ma + 4];
            const float4 b0 = *(const float4*)&Bs[k][mb];
            const float4 b1 = *(const float4*)&Bs[k][mb + 4];
            const float ar[8] = {a0.x, a0.y, a0.z, a0.w, a1.x, a1.y, a1.z, a1.w};
            const float br[8] = {b0.x, b0.y, b0.z, b0.w, b1.x, b1.y, b1.z, b1.w};
#pragma unroll
            for (int i = 0; i < 8; ++i)
#pragma unroll
                for (int j = 0; j < 8; ++j)
                    acc[i][j] = fmaf(ar[i], br[j], acc[i][j]);
        }
        __syncthreads();
    }

    float* outp = Cp + (size_t)blockIdx.z * M * ldc;
    const int row0 = by * 128 + ty * 8;
    const int col0 = bx * 128 + tx * 8;
#pragma unroll
    for (int i = 0; i < 8; ++i) {
        float4 w0; w0.x = acc[i][0]; w0.y = acc[i][1]; w0.z = acc[i][2]; w0.w = acc[i][3];
        float4 w1; w1.x = acc[i][4]; w1.y = acc[i][5]; w1.z = acc[i][6]; w1.w = acc[i][7];
        *(float4*)(outp + (size_t)(row0 + i) * ldc + col0) = w0;
        *(float4*)(outp + (size_t)(row0 + i) * ldc + col0 + 4) = w1;
    }
}

// h = relu(p0 + p1 + bias)   (layer-0 combine, N=512)
__global__ __launch_bounds__(256)
void combine_relu(const float* __restrict__ p0, const float* __restrict__ p1,
                  const float* __restrict__ bias, float* __restrict__ hout)
{
    const int idx = blockIdx.x * 256 + threadIdx.x;
    const float4 a = ((const float4*)p0)[idx];
    const float4 b = ((const float4*)p1)[idx];
    const float4 bs = *(const float4*)&bias[(idx & 127) * 4];
    float4 o;
    o.x = fmaxf(a.x + b.x + bs.x, 0.0f);
    o.y = fmaxf(a.y + b.y + bs.y, 0.0f);
    o.z = fmaxf(a.z + b.z + bs.z, 0.0f);
    o.w = fmaxf(a.w + b.w + bs.w, 0.0f);
    ((float4*)hout)[idx] = o;
}

// layer-1 combine (4 split-K partials + bias) fused with row-norm:
// e[row] = sum_s p_s[row] + b1 ; dvec[row] = ||e[row]||^2. One wave per row.
__global__ __launch_bounds__(256)
void rownorm_combine(const float* __restrict__ p, size_t pstride,
                     const float* __restrict__ bias,
                     float* __restrict__ e, float* __restrict__ dvec)
{
    const int wid = (blockIdx.x * 256 + threadIdx.x) >> 6;   // row 0..4095
    const int lane = threadIdx.x & 63;
    const size_t off = (size_t)wid * EDIM + lane * 4;
    const float4 a = *(const float4*)(p + off);
    const float4 b = *(const float4*)(p + pstride + off);
    const float4 c = *(const float4*)(p + 2 * pstride + off);
    const float4 d = *(const float4*)(p + 3 * pstride + off);
    const float4 bs = *(const float4*)&bias[lane * 4];
    float4 v;
    v.x = a.x + b.x + c.x + d.x + bs.x;
    v.y = a.y + b.y + c.y + d.y + bs.y;
    v.z = a.z + b.z + c.z + d.z + bs.z;
    v.w = a.w + b.w + c.w + d.w + bs.w;
    *(float4*)(e + off) = v;
    float s = v.x * v.x + v.y * v.y + v.z * v.z + v.w * v.w;
#pragma unroll
    for (int o = 32; o; o >>= 1) s += __shfl_xor(s, o);
    if (lane == 0) dvec[wid] = s;
}

// ---------------------------------------------------------------------------
// Correlation GEMM + D epilogue: 128x128 tile, BK=16, 8x8 microtile.
// ---------------------------------------------------------------------------
__global__ __launch_bounds__(256)
void gemm_corr(const float* __restrict__ E, float* __restrict__ D,
               const float* __restrict__ dvec)
{
    __shared__ float As[16][140];
    __shared__ float Bs[16][140];
    const int z = blockIdx.z;
    const float* Eb = E + (size_t)z * NTOK * EDIM;
    float* Db = D + (size_t)z * NTOK * NTOK;
    const int t = threadIdx.x;
    const int tx = t & 15, ty = t >> 4;
    const int by = blockIdx.y, bx = blockIdx.x;
    const int fq = t & 3, lr = t >> 2;

    float acc[8][8] = {};
    for (int kt = 0; kt < EDIM / 16; ++kt) {
#pragma unroll
        for (int h = 0; h < 2; ++h) {
            const int r = lr + h * 64;
            const int rr = r + 4 * (r >> 5);
            const float4 av = *(const float4*)(Eb + (size_t)(by * 128 + r) * EDIM + kt * 16 + fq * 4);
            As[fq * 4 + 0][rr] = av.x; As[fq * 4 + 1][rr] = av.y;
            As[fq * 4 + 2][rr] = av.z; As[fq * 4 + 3][rr] = av.w;
            const float4 bv = *(const float4*)(Eb + (size_t)(bx * 128 + r) * EDIM + kt * 16 + fq * 4);
            Bs[fq * 4 + 0][rr] = bv.x; Bs[fq * 4 + 1][rr] = bv.y;
            Bs[fq * 4 + 2][rr] = bv.z; Bs[fq * 4 + 3][rr] = bv.w;
        }
        __syncthreads();
        const int ma = 8 * ty + 4 * (ty >> 2);
        const int mb = 8 * tx + 4 * (tx >> 2);
#pragma unroll
        for (int k = 0; k < 16; ++k) {
            const float4 a0 = *(const float4*)&As[k][ma];
            const float4 a1 = *(const float4*)&As[k][ma + 4];
            const float4 b0 = *(const float4*)&Bs[k][mb];
            const float4 b1 = *(const float4*)&Bs[k][mb + 4];
            const float ar[8] = {a0.x, a0.y, a0.z, a0.w, a1.x, a1.y, a1.z, a1.w};
            const float br[8] = {b0.x, b0.y, b0.z, b0.w, b1.x, b1.y, b1.z, b1.w};
#pragma unroll
            for (int i = 0; i < 8; ++i)
#pragma unroll
                for (int j = 0; j < 8; ++j)
                    acc[i][j] = fmaf(ar[i], br[j], acc[i][j]);
        }
        __syncthreads();
    }

    const int row0 = by * 128 + ty * 8;
    const int col0 = bx * 128 + tx * 8;
    float di[8], dj[8];
#pragma unroll
    for (int i = 0; i < 8; ++i) di[i] = dvec[z * NTOK + row0 + i];
#pragma unroll
    for (int j = 0; j < 8; ++j) dj[j] = dvec[z * NTOK + col0 + j];
#pragma unroll
    for (int i = 0; i < 8; ++i) {
        float o[8];
#pragma unroll
        for (int j = 0; j < 8; ++j) {
            const float den = sqrtf(fmaxf(di[i] * dj[j], 1e-8f));
            o[j] = 0.5f * (1.0f - acc[i][j] / den);
        }
        float4 w0; w0.x = o[0]; w0.y = o[1]; w0.z = o[2]; w0.w = o[3];
        float4 w1; w1.x = o[4]; w1.y = o[5]; w1.z = o[6]; w1.w = o[7];
        *(float4*)(Db + (size_t)(row0 + i) * NTOK + col0) = w0;
        *(float4*)(Db + (size_t)(row0 + i) * NTOK + col0 + 4) = w1;
    }
}

// Row-wise inclusive scan of D (f32) into R rows 1..N (f64). R[r][0]=0.
__global__ __launch_bounds__(256)
void sat_row_kernel(const float* __restrict__ D, double* __restrict__ R)
{
    const int b = blockIdx.y;
    const int r = blockIdx.x + 1;
    const float* drow = D + (size_t)b * NTOK * NTOK + (size_t)(r - 1) * NTOK;
    double* rrow = R + (size_t)b * ST2 + (size_t)r * NP1;
    const int t = threadIdx.x, lane = t & 63, wv = t >> 6;
    __shared__ double wtot[4];
    double carry = 0.0;
    if (t == 0) rrow[0] = 0.0;
    for (int ch = 0; ch < NTOK / 256; ++ch) {
        double v = (double)drow[ch * 256 + t];
#pragma unroll
        for (int d = 1; d < 64; d <<= 1) {
            const double u = __shfl_up(v, (unsigned)d, 64);
            if (lane >= d) v += u;
        }
        if (lane == 63) wtot[wv] = v;
        __syncthreads();
        double pre = carry;
        for (int ww = 0; ww < wv; ++ww) pre += wtot[ww];
        const double tot = carry + wtot[0] + wtot[1] + wtot[2] + wtot[3];
        rrow[ch * 256 + t + 1] = v + pre;
        __syncthreads();
        carry = tot;
    }
}

// strip sums: aux[s][c] = sum_{r in strip s} R[r][c]   (strips of 64 rows)
__global__ void satc1(const double* __restrict__ R, double* __restrict__ aux)
{
    const int b = blockIdx.z, s = blockIdx.y, cb = blockIdx.x;
    if ((cb + 1) * 256 <= s * SROWS) return;
    const int c = cb * 256 + threadIdx.x;
    if (c > NTOK) return;
    const double* rb = R + (size_t)b * ST2;
    double tt = 0.0;
    const int r0 = s * SROWS + 1;
    for (int r = r0; r < r0 + SROWS; ++r) tt += rb[(size_t)r * NP1 + c];
    aux[(size_t)(b * STRIPS + s) * NP1 + c] = tt;
}
// exclusive prefix over strips + fused diag: dg[c] = prefix@strip(c) + partial rows
__global__ void satc2_diag(const double* __restrict__ R, double* __restrict__ aux,
                           double* __restrict__ dg)
{
    const int b = blockIdx.y;
    const int c = blockIdx.x * 256 + threadIdx.x;
    if (c > NTOK) return;
    const int s0 = (c == 0) ? -1 : (c - 1) / SROWS;
    double pre = 0.0;
    double run = 0.0;
    for (int s = 0; s < STRIPS; ++s) {
        const size_t id = (size_t)(b * STRIPS + s) * NP1 + c;
        const double tt = aux[id]; aux[id] = run;
        if (s == s0) pre = run;
        run += tt;
    }
    if (c == 0) { dg[b * NP1] = 0.0; return; }
    const double* rb = R + (size_t)b * ST2;
    const int r0 = s0 * SROWS + 1;
    for (int r = r0; r <= c; ++r)
        pre += rb[(size_t)r * NP1 + c];
    dg[b * NP1 + c] = pre;
}
// Column pass emitting Bsum directly (f32, upper triangle) + C0.
__global__ __launch_bounds__(256)
void satc3_bsum(const double* __restrict__ R, const double* __restrict__ aux,
                const double* __restrict__ dg,
                float* __restrict__ Bsum, float* __restrict__ C0)
{
    const int b = blockIdx.z, s = blockIdx.y, cb = blockIdx.x;
    const int r0 = s * SROWS + 1;
    if (r0 >= (cb + 1) * 256) return;
    const int c = cb * 256 + threadIdx.x;
    if (c > NTOK || c == 0) return;
    const double* rb = R + (size_t)b * ST2;
    const double* dgb = dg + b * NP1;
    const double dgc = dgb[c];
    float* Bb = Bsum + (size_t)b * NTOK * NTOK;
    float* C0b = C0 + b * NTOK;
    if (s == 0) {
        const float v0 = (float)dgc;
        Bb[c - 1] = v0;
        if (c == NTOK) C0b[0] = v0;
    }
    double run = aux[(size_t)(b * STRIPS + s) * NP1 + c];
    const int rend = r0 + SROWS;
    for (int r = r0; r < rend; ++r) {
        run += rb[(size_t)r * NP1 + c];
        if (r < c) {
            const float v = (float)(dgc + dgb[r] - 2.0 * run);
            Bb[(size_t)r * NTOK + (c - 1)] = v;
            if (c == NTOK) C0b[r] = v;
        }
    }
}

// ---------------------------------------------------------------------------
// DP v11: fence-free sync, register body, dwordx4-sc1 cs fill, fused finalize.
// ---------------------------------------------------------------------------
#define DP_BX 128
#define DP_PAIRS 8
#define RBBIG 3.0e37f

__device__ inline void cstore(float* p, float v)
{
    __hip_atomic_store(p, v, __ATOMIC_RELAXED, __HIP_MEMORY_SCOPE_AGENT);
}

__device__ inline void wait_flags(const int* flagsb, int need)
{
    if (threadIdx.x < DP_BX) {
        const int* f = flagsb + threadIdx.x * 4;
        while (__hip_atomic_load(f, __ATOMIC_RELAXED, __HIP_MEMORY_SCOPE_AGENT) < need)
            __builtin_amdgcn_s_sleep(1);
    }
    __syncthreads();
}

__device__ inline void publish(int* myflag, int val)
{
    asm volatile("s_waitcnt vmcnt(0)" ::: "memory");
    __syncthreads();
    if (threadIdx.x == 0)
        __hip_atomic_store(myflag, val, __ATOMIC_RELAXED, __HIP_MEMORY_SCOPE_AGENT);
}

template<int NC>
__device__ inline void load_rb(const float* __restrict__ brow, int colbase, int lane,
                               float (&rb)[NC])
{
#pragma unroll
    for (int c = 0; c < NC; ++c) {
        const int col = colbase + lane + c * 64;
        rb[c] = (col < NTOK) ? brow[col] : RBBIG;
    }
}

template<int NC>
__device__ inline float pass1(const float (&rb)[NC], const float* __restrict__ cs,
                              int coff, int V, int lane)
{
    float mn = FLT_MAX;
#pragma unroll
    for (int c = 0; c < NC; ++c) {
        const int idx = lane + c * 64;
        if (idx < V) mn = fminf(mn, rb[c] + cs[coff + idx]);
    }
#pragma unroll
    for (int o = 32; o; o >>= 1) mn = fminf(mn, __shfl_xor(mn, o));
    return mn;
}

template<int NC>
__device__ inline void pass2(const float (&rb)[NC], const float* __restrict__ cs,
                             int coff, int V, float mn, int lane, float (&ac)[NC])
{
    float w[NC];
    float s = 0.0f;
#pragma unroll
    for (int c = 0; c < NC; ++c) {
        const int idx = lane + c * 64;
        float x = 0.0f;
        if (idx < V) x = __expf(mn - (rb[c] + cs[coff + idx]));
        w[c] = x;
        s += x;
    }
#pragma unroll
    for (int o = 32; o; o >>= 1) s += __shfl_xor(s, o);
    const float inv = 1.0f / s;
#pragma unroll
    for (int c = 0; c < NC; ++c) ac[c] = __builtin_fmaf(w[c], inv, ac[c]);
}

template<int NC>
__device__ inline void merge_acc(const float (&ac)[NC], int base, int lane,
                                 float* __restrict__ acc_lds)
{
#pragma unroll
    for (int c = 0; c < NC; ++c) {
        const int col = base + lane + c * 64;
        if (col < NTOK && ac[c] != 0.0f) atomicAdd(&acc_lds[col], ac[c]);
    }
}

__global__ __launch_bounds__(256, 1)
void dp_fused_kernel(const float* __restrict__ Bsum,
                     float* __restrict__ Ca, float* __restrict__ Cb,
                     float* __restrict__ tsum, int* __restrict__ flags,
                     float* __restrict__ out)
{
    __shared__ float cs[NTOK];
    __shared__ float acc_lds[NTOK];
    const int b = blockIdx.y;
    const int t = threadIdx.x, lane = t & 63, wv = t >> 6;
    const float* Bb = Bsum + (size_t)b * NTOK * NTOK;
    const int pbase = blockIdx.x * DP_PAIRS;
    int* flagsb = flags + b * DP_BX * 4;
    int* myflag = flagsb + blockIdx.x * 4;

    const int p0 = pbase + wv * 2, p1 = p0 + 1;
    const int i1_0 = NTOK - 1 - p0, i1_1 = NTOK - 1 - p1;

    float rbA0[32], rbB0[16], rbA1[32], rbB1[16];
    load_rb<32>(Bb + (size_t)p0 * NTOK, p0, lane, rbA0);
    load_rb<16>(Bb + (size_t)i1_0 * NTOK, i1_0, lane, rbB0);
    load_rb<32>(Bb + (size_t)p1 * NTOK, p1, lane, rbA1);
    load_rb<16>(Bb + (size_t)i1_1 * NTOK, i1_1, lane, rbB1);

    float acA0[32] = {}, acB0[16] = {}, acA1[32] = {}, acB1[16] = {};

    for (int j = t; j < NTOK; j += 256) acc_lds[j] = 0.0f;

    // C0 (shifted): Csh[i-1] = Bsum[i][N-1]
    if (t < DP_PAIRS) {
        const int p = pbase + t, i1 = NTOK - 1 - p;
        if (p > 0) cstore(&Ca[b * NTOK + p - 1], Bb[(size_t)p * NTOK + NTOK - 1]);
        cstore(&Ca[b * NTOK + i1 - 1], Bb[(size_t)i1 * NTOK + NTOK - 1]);
    }
    publish(myflag, 0);

    const float* Cr = Ca;
    float* Cn = Cb;

    for (int k = 1; k < KSEG; ++k) {
        wait_flags(flagsb, k - 1);
        {
            const float* base  = Cr + b * NTOK + t * 4;
            const float* base2 = base + 1024;
            float4 va, vb;
            asm volatile(
                "global_load_dwordx4 %0, %2, off sc1\n\t"
                "global_load_dwordx4 %1, %3, off sc1\n\t"
                "s_waitcnt vmcnt(0)"
                : "=&v"(va), "=&v"(vb)
                : "v"(base), "v"(base2)
                : "memory");
            *(float4*)&cs[t * 4] = va;
            *(float4*)&cs[t * 4 + 1024] = vb;
        }
        __syncthreads();
        float* Cnb = Cn + b * NTOK;
        const int jmax = NTOK - k;

        const int VA0 = jmax - p0, VA1 = jmax - p1;
        const int VB0 = p0 + 1 - k, VB1 = p1 + 1 - k;
        const float mnA0 = pass1<32>(rbA0, cs, p0, VA0, lane);
        float mnB0 = 0.0f, mnB1 = 0.0f;
        if (p0 >= k) mnB0 = pass1<16>(rbB0, cs, i1_0, VB0, lane);
        const float mnA1 = pass1<32>(rbA1, cs, p1, VA1, lane);
        if (p1 >= k) mnB1 = pass1<16>(rbB1, cs, i1_1, VB1, lane);
        if (lane == 0) {
            if (p0 > 0) cstore(&Cnb[p0 - 1], mnA0);
            cstore(&Cnb[i1_0 - 1], (p0 >= k) ? mnB0 : 0.0f);
            cstore(&Cnb[p1 - 1], mnA1);
            cstore(&Cnb[i1_1 - 1], (p1 >= k) ? mnB1 : 0.0f);
        }
        publish(myflag, k);

        pass2<32>(rbA0, cs, p0, VA0, mnA0, lane, acA0);
        if (p0 >= k) pass2<16>(rbB0, cs, i1_0, VB0, mnB0, lane, acB0);
        pass2<32>(rbA1, cs, p1, VA1, mnA1, lane, acA1);
        if (p1 >= k) pass2<16>(rbB1, cs, i1_1, VB1, mnB1, lane, acB1);

        float* tmp = (float*)Cr; Cr = Cn; Cn = tmp;
    }

    // merge: regs -> LDS -> global tsum (device-scope atomics at MALL)
    __syncthreads();
    merge_acc<32>(acA0, p0, lane, acc_lds);
    merge_acc<16>(acB0, i1_0, lane, acc_lds);
    merge_acc<32>(acA1, p1, lane, acc_lds);
    merge_acc<16>(acB1, i1_1, lane, acc_lds);
    __syncthreads();
    float* ts = tsum + b * NTOK;
    for (int j = t; j < NTOK; j += 256) {
        const float v = acc_lds[j];
        if (v != 0.0f) atomicAdd(&ts[j], v);
    }
    // fused finalize: one more sync round, then blocks bx<8 emit out
    publish(myflag, KSEG);
    wait_flags(flagsb, KSEG);
    if (blockIdx.x < 8) {
        const int j = blockIdx.x * 256 + t;
        float tsv = __hip_atomic_load(&ts[j], __ATOMIC_RELAXED, __HIP_MEMORY_SCOPE_AGENT);
        int steps = NTOK - 1 - j;
        if (steps > KSEG - 1) steps = KSEG - 1;
        float tc = (float)(j + 1) * (float)steps;
        if (j == NTOK - 1) { tsv += (float)NTOK; tc += (float)NTOK; }
        out[b * NTOK + j] = tsv / tc;
    }
}

// ---- fallback path (29 launches) ----
__global__ __launch_bounds__(256)
void dp_step_kernel(const float* __restrict__ Bsum, const float* __restrict__ Cprev,
                    float* __restrict__ Cnext, float* __restrict__ tsum, int kk)
{
    __shared__ float cs[NTOK];
    __shared__ float acc[NTOK];
    const int b = blockIdx.y;
    const int t = threadIdx.x, lane = t & 63, wv = t >> 6;
    const float* Cp = Cprev + b * NTOK;
    for (int j = t; j < NTOK; j += 256) {
        cs[j] = (j < NTOK - 1) ? Cp[j + 1] : 0.0f;
        acc[j] = 0.0f;
    }
    __syncthreads();
    const int jmax = NTOK - kk;
    const int w = blockIdx.x * 4 + wv;
    const float* Bb = Bsum + (size_t)b * NTOK * NTOK;
    float* Cn = Cnext + b * NTOK;
    const int rows[4] = { w, 1023 - w, 1024 + w, 2047 - w };
#pragma unroll
    for (int rr = 0; rr < 4; ++rr) {
        const int i = rows[rr];
        if (i >= jmax) { if (lane == 0) Cn[i] = 0.0f; continue; }
        const float* brow = Bb + (size_t)i * NTOK;
        const int j0 = i + lane;
        float mv[32];
        float mn = FLT_MAX;
#pragma unroll
        for (int c = 0; c < 32; ++c) {
            const int j = j0 + c * 64;
            float v = FLT_MAX;
            if (j < jmax) v = brow[j] + cs[j];
            mv[c] = v;
            mn = fminf(mn, v);
        }
#pragma unroll
        for (int off = 32; off; off >>= 1) mn = fminf(mn, __shfl_xor(mn, off));
        if (lane == 0) Cn[i] = mn;
        float s = 0.0f;
#pragma unroll
        for (int c = 0; c < 32; ++c) {
            const int j = j0 + c * 64;
            float p = 0.0f;
            if (j < jmax) p = __expf(mn - mv[c]);
            mv[c] = p;
            s += p;
        }
#pragma unroll
        for (int off = 32; off; off >>= 1) s += __shfl_xor(s, off);
        const float inv = 1.0f / s;
#pragma unroll
        for (int c = 0; c < 32; ++c) {
            const int j = j0 + c * 64;
            if (j < jmax) atomicAdd(&acc[j], mv[c] * inv);
        }
    }
    __syncthreads();
    float* ts = tsum + b * NTOK;
    for (int j = t; j < NTOK; j += 256) {
        const float v = acc[j];
        if (v != 0.0f) atomicAdd(&ts[j], v);
    }
}

__global__ void finalize_kernel(const float* __restrict__ tsum, float* __restrict__ out)
{
    const int b = blockIdx.y;
    const int j = blockIdx.x * 256 + threadIdx.x;
    if (j >= NTOK) return;
    float ts = tsum[b * NTOK + j];
    int steps = NTOK - 1 - j;
    if (steps > KSEG - 1) steps = KSEG - 1;
    float tc = (float)(j + 1) * (float)steps;
    if (j == NTOK - 1) { ts += (float)NTOK; tc += (float)NTOK; }
    out[b * NTOK + j] = ts / tc;
}

extern "C" void kernel_launch(void* const* d_in, const int* in_sizes, int n_in,
                              void* d_out, int out_size, void* d_ws, size_t ws_size,
                              hipStream_t stream)
{
    const float* x  = (const float*)d_in[0];
    const float* W0 = (const float*)d_in[1];
    const float* b0 = (const float*)d_in[2];
    const float* W1 = (const float*)d_in[3];
    const float* b1 = (const float*)d_in[4];
    float* out = (float*)d_out;

    char* ws = (char*)d_ws;
    size_t off = 0;
    auto alloc = [&](size_t bytes) -> void* {
        void* p = (void*)(ws + off);
        off += (bytes + 255) & ~(size_t)255;
        return p;
    };
    double* Rsc  = (double*)alloc((size_t)BATCH * ST2 * sizeof(double));          // rowscan
    float*  Dm   = (float*) alloc((size_t)BATCH * NTOK * NTOK * sizeof(float));   // D / Bsum / partials
    float*  h    = (float*) alloc((size_t)BATCH * NTOK * HDIM * sizeof(float));
    float*  e    = (float*) alloc((size_t)BATCH * NTOK * EDIM * sizeof(float));
    float*  dvec = (float*) alloc((size_t)BATCH * NTOK * sizeof(float));
    double* dg   = (double*)alloc((size_t)BATCH * NP1 * sizeof(double));
    double* aux  = (double*)alloc((size_t)BATCH * STRIPS * NP1 * sizeof(double));
    float*  CA   = (float*) alloc((size_t)BATCH * NTOK * sizeof(float));
    float*  CB   = (float*) alloc((size_t)BATCH * NTOK * sizeof(float));
    float*  tsum = (float*) alloc((size_t)BATCH * NTOK * sizeof(float));
    int*    flags= (int*)   alloc((size_t)BATCH * DP_BX * 4 * sizeof(int));
    (void)ws_size; (void)in_sizes; (void)n_in; (void)out_size;

    hipMemsetAsync(tsum, 0, (size_t)BATCH * NTOK * sizeof(float), stream);
    hipMemsetAsync(flags, 0xFF, (size_t)BATCH * DP_BX * 4 * sizeof(int), stream);

    const int M = BATCH * NTOK;
    // Layer 0 (split-K=2, partials in Dm): h = relu(x @ W0^T + b0)
    gemm_nt128s<<<dim3(HDIM / 128, M / 128, 2), 256, 0, stream>>>(
        x, FDIM, W0, FDIM, Dm, HDIM, M, FDIM / 2);
    combine_relu<<<dim3((M * HDIM / 4) / 256), 256, 0, stream>>>(
        Dm, Dm + (size_t)M * HDIM, b0, h);
    // Layer 1 (split-K=4, partials in Dm): e = h @ W1^T + b1, fused rownorm
    gemm_nt128s<<<dim3(EDIM / 128, M / 128, 4), 256, 0, stream>>>(
        h, HDIM, W1, HDIM, Dm, EDIM, M, HDIM / 4);
    rownorm_combine<<<dim3(M / 4), 256, 0, stream>>>(
        Dm, (size_t)M * EDIM, b1, e, dvec);
    // D (full matrix) into Dm (overwrites partials)
    gemm_corr<<<dim3(NTOK / 128, NTOK / 128, BATCH), 256, 0, stream>>>(e, Dm, dvec);
    // SAT: rowscan -> strip sums -> prefix+diag -> fused Bsum emit
    sat_row_kernel<<<dim3(NTOK, BATCH), 256, 0, stream>>>(Dm, Rsc);
    satc1<<<dim3((NP1 + 255) / 256, STRIPS, BATCH), 256, 0, stream>>>(Rsc, aux);
    satc2_diag<<<dim3((NP1 + 255) / 256, BATCH), 256, 0, stream>>>(Rsc, aux, dg);
    satc3_bsum<<<dim3((NP1 + 255) / 256, STRIPS, BATCH), 256, 0, stream>>>(
        Rsc, aux, dg, Dm, CA);

    // Fused DP + finalize
    void* args[] = { (void*)&Dm, (void*)&CA, (void*)&CB, (void*)&tsum,
                     (void*)&flags, (void*)&out };
    hipError_t err = hipLaunchCooperativeKernel((const void*)dp_fused_kernel,
                                                dim3(DP_BX, BATCH), dim3(256),
                                                args, 0, stream);
    if (err != hipSuccess) {
        float* cp = CA; float* cn = CB;
        for (int kk = 1; kk < KSEG; ++kk) {
            dp_step_kernel<<<dim3(128, BATCH), 256, 0, stream>>>(Dm, cp, cn, tsum, kk);
            float* tmp = cp; cp = cn; cn = tmp;
        }
        finalize_kernel<<<dim3(NTOK / 256, BATCH), 256, 0, stream>>>(tsum, out);
    }
}

// Round 18
// 625.905 us; speedup vs baseline: 1.2838x; 1.0050x over previous
//
#include <hip/hip_runtime.h>
#include <hip/hip_bf16.h>
#include <float.h>

// Problem constants (OSG_C_29987461660961)
#define NTOK 2048
#define FDIM 1024
#define HDIM 512
#define EDIM 256
#define BATCH 2
#define KSEG 30
#define NP1 2049
#define STRIPS 32
#define SROWS 64
static const size_t ST2 = (size_t)NP1 * NP1;   // rowscan per-batch element count

// ---------------------------------------------------------------------------
// Split-K 128x128 / 8x8 GEMM partial (shared by layer 0 and layer 1).
// ---------------------------------------------------------------------------
__global__ __launch_bounds__(256)
void gemm_nt128s(const float* __restrict__ A, int lda,
                 const float* __restrict__ Bm, int ldb,
                 float* __restrict__ Cp, int ldc, int M, int ksplit)
{
    __shared__ float As[16][140];
    __shared__ float Bs[16][140];
    const int t = threadIdx.x;
    const int tx = t & 15, ty = t >> 4;
    const int by = blockIdx.y, bx = blockIdx.x;
    const int k0 = blockIdx.z * ksplit;
    const int fq = t & 3, lr = t >> 2;

    float acc[8][8] = {};
    for (int kt = 0; kt < ksplit / 16; ++kt) {
#pragma unroll
        for (int h = 0; h < 2; ++h) {
            const int r = lr + h * 64;
            const int rr = r + 4 * (r >> 5);
            const float4 av = *(const float4*)(A + (size_t)(by * 128 + r) * lda + k0 + kt * 16 + fq * 4);
            As[fq * 4 + 0][rr] = av.x; As[fq * 4 + 1][rr] = av.y;
            As[fq * 4 + 2][rr] = av.z; As[fq * 4 + 3][rr] = av.w;
            const float4 bv = *(const float4*)(Bm + (size_t)(bx * 128 + r) * ldb + k0 + kt * 16 + fq * 4);
            Bs[fq * 4 + 0][rr] = bv.x; Bs[fq * 4 + 1][rr] = bv.y;
            Bs[fq * 4 + 2][rr] = bv.z; Bs[fq * 4 + 3][rr] = bv.w;
        }
        __syncthreads();
        const int ma = 8 * ty + 4 * (ty >> 2);
        const int mb = 8 * tx + 4 * (tx >> 2);
#pragma unroll
        for (int k = 0; k < 16; ++k) {
            const float4 a0 = *(const float4*)&As[k][ma];
            const float4 a1 = *(const float4*)&As[k][ma + 4];
            const float4 b0 = *(const float4*)&Bs[k][mb];
            const float4 b1 = *(const float4*)&Bs[k][mb + 4];
            const float ar[8] = {a0.x, a0.y, a0.z, a0.w, a1.x, a1.y, a1.z, a1.w};
            const float br[8] = {b0.x, b0.y, b0.z, b0.w, b1.x, b1.y, b1.z, b1.w};
#pragma unroll
            for (int i = 0; i < 8; ++i)
#pragma unroll
                for (int j = 0; j < 8; ++j)
                    acc[i][j] = fmaf(ar[i], br[j], acc[i][j]);
        }
        __syncthreads();
    }

    float* outp = Cp + (size_t)blockIdx.z * M * ldc;
    const int row0 = by * 128 + ty * 8;
    const int col0 = bx * 128 + tx * 8;
#pragma unroll
    for (int i = 0; i < 8; ++i) {
        float4 w0; w0.x = acc[i][0]; w0.y = acc[i][1]; w0.z = acc[i][2]; w0.w = acc[i][3];
        float4 w1; w1.x = acc[i][4]; w1.y = acc[i][5]; w1.z = acc[i][6]; w1.w = acc[i][7];
        *(float4*)(outp + (size_t)(row0 + i) * ldc + col0) = w0;
        *(float4*)(outp + (size_t)(row0 + i) * ldc + col0 + 4) = w1;
    }
}

// h = relu(p0 + p1 + bias)   (layer-0 combine, N=512)
__global__ __launch_bounds__(256)
void combine_relu(const float* __restrict__ p0, const float* __restrict__ p1,
                  const float* __restrict__ bias, float* __restrict__ hout)
{
    const int idx = blockIdx.x * 256 + threadIdx.x;
    const float4 a = ((const float4*)p0)[idx];
    const float4 b = ((const float4*)p1)[idx];
    const float4 bs = *(const float4*)&bias[(idx & 127) * 4];
    float4 o;
    o.x = fmaxf(a.x + b.x + bs.x, 0.0f);
    o.y = fmaxf(a.y + b.y + bs.y, 0.0f);
    o.z = fmaxf(a.z + b.z + bs.z, 0.0f);
    o.w = fmaxf(a.w + b.w + bs.w, 0.0f);
    ((float4*)hout)[idx] = o;
}

// layer-1 combine (4 split-K partials + bias) fused with row-norm.
__global__ __launch_bounds__(256)
void rownorm_combine(const float* __restrict__ p, size_t pstride,
                     const float* __restrict__ bias,
                     float* __restrict__ e, float* __restrict__ dvec)
{
    const int wid = (blockIdx.x * 256 + threadIdx.x) >> 6;
    const int lane = threadIdx.x & 63;
    const size_t off = (size_t)wid * EDIM + lane * 4;
    const float4 a = *(const float4*)(p + off);
    const float4 b = *(const float4*)(p + pstride + off);
    const float4 c = *(const float4*)(p + 2 * pstride + off);
    const float4 d = *(const float4*)(p + 3 * pstride + off);
    const float4 bs = *(const float4*)&bias[lane * 4];
    float4 v;
    v.x = a.x + b.x + c.x + d.x + bs.x;
    v.y = a.y + b.y + c.y + d.y + bs.y;
    v.z = a.z + b.z + c.z + d.z + bs.z;
    v.w = a.w + b.w + c.w + d.w + bs.w;
    *(float4*)(e + off) = v;
    float s = v.x * v.x + v.y * v.y + v.z * v.z + v.w * v.w;
#pragma unroll
    for (int o = 32; o; o >>= 1) s += __shfl_xor(s, o);
    if (lane == 0) dvec[wid] = s;
}

// ---------------------------------------------------------------------------
// Correlation GEMM + D epilogue: 128x128 tile, BK=16, 8x8 microtile.
// ---------------------------------------------------------------------------
__global__ __launch_bounds__(256)
void gemm_corr(const float* __restrict__ E, float* __restrict__ D,
               const float* __restrict__ dvec)
{
    __shared__ float As[16][140];
    __shared__ float Bs[16][140];
    const int z = blockIdx.z;
    const float* Eb = E + (size_t)z * NTOK * EDIM;
    float* Db = D + (size_t)z * NTOK * NTOK;
    const int t = threadIdx.x;
    const int tx = t & 15, ty = t >> 4;
    const int by = blockIdx.y, bx = blockIdx.x;
    const int fq = t & 3, lr = t >> 2;

    float acc[8][8] = {};
    for (int kt = 0; kt < EDIM / 16; ++kt) {
#pragma unroll
        for (int h = 0; h < 2; ++h) {
            const int r = lr + h * 64;
            const int rr = r + 4 * (r >> 5);
            const float4 av = *(const float4*)(Eb + (size_t)(by * 128 + r) * EDIM + kt * 16 + fq * 4);
            As[fq * 4 + 0][rr] = av.x; As[fq * 4 + 1][rr] = av.y;
            As[fq * 4 + 2][rr] = av.z; As[fq * 4 + 3][rr] = av.w;
            const float4 bv = *(const float4*)(Eb + (size_t)(bx * 128 + r) * EDIM + kt * 16 + fq * 4);
            Bs[fq * 4 + 0][rr] = bv.x; Bs[fq * 4 + 1][rr] = bv.y;
            Bs[fq * 4 + 2][rr] = bv.z; Bs[fq * 4 + 3][rr] = bv.w;
        }
        __syncthreads();
        const int ma = 8 * ty + 4 * (ty >> 2);
        const int mb = 8 * tx + 4 * (tx >> 2);
#pragma unroll
        for (int k = 0; k < 16; ++k) {
            const float4 a0 = *(const float4*)&As[k][ma];
            const float4 a1 = *(const float4*)&As[k][ma + 4];
            const float4 b0 = *(const float4*)&Bs[k][mb];
            const float4 b1 = *(const float4*)&Bs[k][mb + 4];
            const float ar[8] = {a0.x, a0.y, a0.z, a0.w, a1.x, a1.y, a1.z, a1.w};
            const float br[8] = {b0.x, b0.y, b0.z, b0.w, b1.x, b1.y, b1.z, b1.w};
#pragma unroll
            for (int i = 0; i < 8; ++i)
#pragma unroll
                for (int j = 0; j < 8; ++j)
                    acc[i][j] = fmaf(ar[i], br[j], acc[i][j]);
        }
        __syncthreads();
    }

    const int row0 = by * 128 + ty * 8;
    const int col0 = bx * 128 + tx * 8;
    float di[8], dj[8];
#pragma unroll
    for (int i = 0; i < 8; ++i) di[i] = dvec[z * NTOK + row0 + i];
#pragma unroll
    for (int j = 0; j < 8; ++j) dj[j] = dvec[z * NTOK + col0 + j];
#pragma unroll
    for (int i = 0; i < 8; ++i) {
        float o[8];
#pragma unroll
        for (int j = 0; j < 8; ++j) {
            const float den = sqrtf(fmaxf(di[i] * dj[j], 1e-8f));
            o[j] = 0.5f * (1.0f - acc[i][j] / den);
        }
        float4 w0; w0.x = o[0]; w0.y = o[1]; w0.z = o[2]; w0.w = o[3];
        float4 w1; w1.x = o[4]; w1.y = o[5]; w1.z = o[6]; w1.w = o[7];
        *(float4*)(Db + (size_t)(row0 + i) * NTOK + col0) = w0;
        *(float4*)(Db + (size_t)(row0 + i) * NTOK + col0 + 4) = w1;
    }
}

// Row-wise inclusive scan of D (f32) into R rows 1..N (f64), TRIANGULAR:
// only cols >= r-1 are stored (R[r][c] with c < r-1 is never consumed).
__global__ __launch_bounds__(256)
void sat_row_kernel(const float* __restrict__ D, double* __restrict__ R)
{
    const int b = blockIdx.y;
    const int r = blockIdx.x + 1;
    const float* drow = D + (size_t)b * NTOK * NTOK + (size_t)(r - 1) * NTOK;
    double* rrow = R + (size_t)b * ST2 + (size_t)r * NP1;
    const int t = threadIdx.x, lane = t & 63, wv = t >> 6;
    __shared__ double wtot[4];
    double carry = 0.0;
    for (int ch = 0; ch < NTOK / 256; ++ch) {
        double v = (double)drow[ch * 256 + t];
#pragma unroll
        for (int d = 1; d < 64; d <<= 1) {
            const double u = __shfl_up(v, (unsigned)d, 64);
            if (lane >= d) v += u;
        }
        if (lane == 63) wtot[wv] = v;
        __syncthreads();
        double pre = carry;
        for (int ww = 0; ww < wv; ++ww) pre += wtot[ww];
        const double tot = carry + wtot[0] + wtot[1] + wtot[2] + wtot[3];
        const int col = ch * 256 + t + 1;
        if (col >= r - 1)                      // triangular store
            rrow[col] = v + pre;
        __syncthreads();
        carry = tot;
    }
}

// strip sums: aux[s][c] = sum_{r in strip s} R[r][c]   (strips of 64 rows)
// Only consumed when all strip rows < c -> skip blocks fully above diag,
// and clamp is unnecessary for valid consumers (their rows are all < c).
__global__ void satc1(const double* __restrict__ R, double* __restrict__ aux)
{
    const int b = blockIdx.z, s = blockIdx.y, cb = blockIdx.x;
    if ((cb + 1) * 256 <= s * SROWS) return;
    const int c = cb * 256 + threadIdx.x;
    if (c > NTOK) return;
    const double* rb = R + (size_t)b * ST2;
    double tt = 0.0;
    const int r0 = s * SROWS + 1;
    // rows r with c >= r-1 are stored; consumed aux needs rows < c only.
    const int rend = min(r0 + SROWS, c + 2);
    for (int r = r0; r < rend; ++r) tt += rb[(size_t)r * NP1 + c];
    aux[(size_t)(b * STRIPS + s) * NP1 + c] = tt;
}
// exclusive prefix over strips + fused diag
__global__ void satc2_diag(const double* __restrict__ R, double* __restrict__ aux,
                           double* __restrict__ dg)
{
    const int b = blockIdx.y;
    const int c = blockIdx.x * 256 + threadIdx.x;
    if (c > NTOK) return;
    const int s0 = (c == 0) ? -1 : (c - 1) / SROWS;
    double pre = 0.0;
    double run = 0.0;
    for (int s = 0; s < STRIPS; ++s) {
        const size_t id = (size_t)(b * STRIPS + s) * NP1 + c;
        const double tt = aux[id]; aux[id] = run;
        if (s == s0) pre = run;
        run += tt;
    }
    if (c == 0) { dg[b * NP1] = 0.0; return; }
    const double* rb = R + (size_t)b * ST2;
    const int r0 = s0 * SROWS + 1;
    for (int r = r0; r <= c; ++r)
        pre += rb[(size_t)r * NP1 + c];
    dg[b * NP1 + c] = pre;
}
// Column pass emitting Bsum directly (f32, upper triangle) + C0.
__global__ __launch_bounds__(256)
void satc3_bsum(const double* __restrict__ R, const double* __restrict__ aux,
                const double* __restrict__ dg,
                float* __restrict__ Bsum, float* __restrict__ C0)
{
    const int b = blockIdx.z, s = blockIdx.y, cb = blockIdx.x;
    const int r0 = s * SROWS + 1;
    if (r0 >= (cb + 1) * 256) return;
    const int c = cb * 256 + threadIdx.x;
    if (c > NTOK || c == 0) return;
    const double* rb = R + (size_t)b * ST2;
    const double* dgb = dg + b * NP1;
    const double dgc = dgb[c];
    float* Bb = Bsum + (size_t)b * NTOK * NTOK;
    float* C0b = C0 + b * NTOK;
    if (s == 0) {
        const float v0 = (float)dgc;
        Bb[c - 1] = v0;
        if (c == NTOK) C0b[0] = v0;
    }
    double run = aux[(size_t)(b * STRIPS + s) * NP1 + c];
    const int rend = min(r0 + SROWS, c);       // emit only r < c; later rows unused
    for (int r = r0; r < rend; ++r) {
        run += rb[(size_t)r * NP1 + c];
        const float v = (float)(dgc + dgb[r] - 2.0 * run);
        Bb[(size_t)r * NTOK + (c - 1)] = v;
        if (c == NTOK) C0b[r] = v;
    }
}

// ---------------------------------------------------------------------------
// DP v11: fence-free sync, register body, dwordx4-sc1 cs fill, fused finalize.
// ---------------------------------------------------------------------------
#define DP_BX 128
#define DP_PAIRS 8
#define RBBIG 3.0e37f

__device__ inline void cstore(float* p, float v)
{
    __hip_atomic_store(p, v, __ATOMIC_RELAXED, __HIP_MEMORY_SCOPE_AGENT);
}

__device__ inline void wait_flags(const int* flagsb, int need)
{
    if (threadIdx.x < DP_BX) {
        const int* f = flagsb + threadIdx.x * 4;
        while (__hip_atomic_load(f, __ATOMIC_RELAXED, __HIP_MEMORY_SCOPE_AGENT) < need)
            __builtin_amdgcn_s_sleep(1);
    }
    __syncthreads();
}

__device__ inline void publish(int* myflag, int val)
{
    asm volatile("s_waitcnt vmcnt(0)" ::: "memory");
    __syncthreads();
    if (threadIdx.x == 0)
        __hip_atomic_store(myflag, val, __ATOMIC_RELAXED, __HIP_MEMORY_SCOPE_AGENT);
}

template<int NC>
__device__ inline void load_rb(const float* __restrict__ brow, int colbase, int lane,
                               float (&rb)[NC])
{
#pragma unroll
    for (int c = 0; c < NC; ++c) {
        const int col = colbase + lane + c * 64;
        rb[c] = (col < NTOK) ? brow[col] : RBBIG;
    }
}

template<int NC>
__device__ inline float pass1(const float (&rb)[NC], const float* __restrict__ cs,
                              int coff, int V, int lane)
{
    float mn = FLT_MAX;
#pragma unroll
    for (int c = 0; c < NC; ++c) {
        const int idx = lane + c * 64;
        if (idx < V) mn = fminf(mn, rb[c] + cs[coff + idx]);
    }
#pragma unroll
    for (int o = 32; o; o >>= 1) mn = fminf(mn, __shfl_xor(mn, o));
    return mn;
}

template<int NC>
__device__ inline void pass2(const float (&rb)[NC], const float* __restrict__ cs,
                             int coff, int V, float mn, int lane, float (&ac)[NC])
{
    float w[NC];
    float s = 0.0f;
#pragma unroll
    for (int c = 0; c < NC; ++c) {
        const int idx = lane + c * 64;
        float x = 0.0f;
        if (idx < V) x = __expf(mn - (rb[c] + cs[coff + idx]));
        w[c] = x;
        s += x;
    }
#pragma unroll
    for (int o = 32; o; o >>= 1) s += __shfl_xor(s, o);
    const float inv = 1.0f / s;
#pragma unroll
    for (int c = 0; c < NC; ++c) ac[c] = __builtin_fmaf(w[c], inv, ac[c]);
}

template<int NC>
__device__ inline void merge_acc(const float (&ac)[NC], int base, int lane,
                                 float* __restrict__ acc_lds)
{
#pragma unroll
    for (int c = 0; c < NC; ++c) {
        const int col = base + lane + c * 64;
        if (col < NTOK && ac[c] != 0.0f) atomicAdd(&acc_lds[col], ac[c]);
    }
}

__global__ __launch_bounds__(256, 1)
void dp_fused_kernel(const float* __restrict__ Bsum,
                     float* __restrict__ Ca, float* __restrict__ Cb,
                     float* __restrict__ tsum, int* __restrict__ flags,
                     float* __restrict__ out)
{
    __shared__ float cs[NTOK];
    __shared__ float acc_lds[NTOK];
    const int b = blockIdx.y;
    const int t = threadIdx.x, lane = t & 63, wv = t >> 6;
    const float* Bb = Bsum + (size_t)b * NTOK * NTOK;
    const int pbase = blockIdx.x * DP_PAIRS;
    int* flagsb = flags + b * DP_BX * 4;
    int* myflag = flagsb + blockIdx.x * 4;

    const int p0 = pbase + wv * 2, p1 = p0 + 1;
    const int i1_0 = NTOK - 1 - p0, i1_1 = NTOK - 1 - p1;

    float rbA0[32], rbB0[16], rbA1[32], rbB1[16];
    load_rb<32>(Bb + (size_t)p0 * NTOK, p0, lane, rbA0);
    load_rb<16>(Bb + (size_t)i1_0 * NTOK, i1_0, lane, rbB0);
    load_rb<32>(Bb + (size_t)p1 * NTOK, p1, lane, rbA1);
    load_rb<16>(Bb + (size_t)i1_1 * NTOK, i1_1, lane, rbB1);

    float acA0[32] = {}, acB0[16] = {}, acA1[32] = {}, acB1[16] = {};

    for (int j = t; j < NTOK; j += 256) acc_lds[j] = 0.0f;

    // C0 (shifted): Csh[i-1] = Bsum[i][N-1]
    if (t < DP_PAIRS) {
        const int p = pbase + t, i1 = NTOK - 1 - p;
        if (p > 0) cstore(&Ca[b * NTOK + p - 1], Bb[(size_t)p * NTOK + NTOK - 1]);
        cstore(&Ca[b * NTOK + i1 - 1], Bb[(size_t)i1 * NTOK + NTOK - 1]);
    }
    publish(myflag, 0);

    const float* Cr = Ca;
    float* Cn = Cb;

    for (int k = 1; k < KSEG; ++k) {
        wait_flags(flagsb, k - 1);
        {
            const float* base  = Cr + b * NTOK + t * 4;
            const float* base2 = base + 1024;
            float4 va, vb;
            asm volatile(
                "global_load_dwordx4 %0, %2, off sc1\n\t"
                "global_load_dwordx4 %1, %3, off sc1\n\t"
                "s_waitcnt vmcnt(0)"
                : "=&v"(va), "=&v"(vb)
                : "v"(base), "v"(base2)
                : "memory");
            *(float4*)&cs[t * 4] = va;
            *(float4*)&cs[t * 4 + 1024] = vb;
        }
        __syncthreads();
        float* Cnb = Cn + b * NTOK;
        const int jmax = NTOK - k;

        const int VA0 = jmax - p0, VA1 = jmax - p1;
        const int VB0 = p0 + 1 - k, VB1 = p1 + 1 - k;
        const float mnA0 = pass1<32>(rbA0, cs, p0, VA0, lane);
        float mnB0 = 0.0f, mnB1 = 0.0f;
        if (p0 >= k) mnB0 = pass1<16>(rbB0, cs, i1_0, VB0, lane);
        const float mnA1 = pass1<32>(rbA1, cs, p1, VA1, lane);
        if (p1 >= k) mnB1 = pass1<16>(rbB1, cs, i1_1, VB1, lane);
        if (lane == 0) {
            if (p0 > 0) cstore(&Cnb[p0 - 1], mnA0);
            cstore(&Cnb[i1_0 - 1], (p0 >= k) ? mnB0 : 0.0f);
            cstore(&Cnb[p1 - 1], mnA1);
            cstore(&Cnb[i1_1 - 1], (p1 >= k) ? mnB1 : 0.0f);
        }
        publish(myflag, k);

        pass2<32>(rbA0, cs, p0, VA0, mnA0, lane, acA0);
        if (p0 >= k) pass2<16>(rbB0, cs, i1_0, VB0, mnB0, lane, acB0);
        pass2<32>(rbA1, cs, p1, VA1, mnA1, lane, acA1);
        if (p1 >= k) pass2<16>(rbB1, cs, i1_1, VB1, mnB1, lane, acB1);

        float* tmp = (float*)Cr; Cr = Cn; Cn = tmp;
    }

    __syncthreads();
    merge_acc<32>(acA0, p0, lane, acc_lds);
    merge_acc<16>(acB0, i1_0, lane, acc_lds);
    merge_acc<32>(acA1, p1, lane, acc_lds);
    merge_acc<16>(acB1, i1_1, lane, acc_lds);
    __syncthreads();
    float* ts = tsum + b * NTOK;
    for (int j = t; j < NTOK; j += 256) {
        const float v = acc_lds[j];
        if (v != 0.0f) atomicAdd(&ts[j], v);
    }
    publish(myflag, KSEG);
    wait_flags(flagsb, KSEG);
    if (blockIdx.x < 8) {
        const int j = blockIdx.x * 256 + t;
        float tsv = __hip_atomic_load(&ts[j], __ATOMIC_RELAXED, __HIP_MEMORY_SCOPE_AGENT);
        int steps = NTOK - 1 - j;
        if (steps > KSEG - 1) steps = KSEG - 1;
        float tc = (float)(j + 1) * (float)steps;
        if (j == NTOK - 1) { tsv += (float)NTOK; tc += (float)NTOK; }
        out[b * NTOK + j] = tsv / tc;
    }
}

// ---- fallback path (29 launches) ----
__global__ __launch_bounds__(256)
void dp_step_kernel(const float* __restrict__ Bsum, const float* __restrict__ Cprev,
                    float* __restrict__ Cnext, float* __restrict__ tsum, int kk)
{
    __shared__ float cs[NTOK];
    __shared__ float acc[NTOK];
    const int b = blockIdx.y;
    const int t = threadIdx.x, lane = t & 63, wv = t >> 6;
    const float* Cp = Cprev + b * NTOK;
    for (int j = t; j < NTOK; j += 256) {
        cs[j] = (j < NTOK - 1) ? Cp[j + 1] : 0.0f;
        acc[j] = 0.0f;
    }
    __syncthreads();
    const int jmax = NTOK - kk;
    const int w = blockIdx.x * 4 + wv;
    const float* Bb = Bsum + (size_t)b * NTOK * NTOK;
    float* Cn = Cnext + b * NTOK;
    const int rows[4] = { w, 1023 - w, 1024 + w, 2047 - w };
#pragma unroll
    for (int rr = 0; rr < 4; ++rr) {
        const int i = rows[rr];
        if (i >= jmax) { if (lane == 0) Cn[i] = 0.0f; continue; }
        const float* brow = Bb + (size_t)i * NTOK;
        const int j0 = i + lane;
        float mv[32];
        float mn = FLT_MAX;
#pragma unroll
        for (int c = 0; c < 32; ++c) {
            const int j = j0 + c * 64;
            float v = FLT_MAX;
            if (j < jmax) v = brow[j] + cs[j];
            mv[c] = v;
            mn = fminf(mn, v);
        }
#pragma unroll
        for (int off = 32; off; off >>= 1) mn = fminf(mn, __shfl_xor(mn, off));
        if (lane == 0) Cn[i] = mn;
        float s = 0.0f;
#pragma unroll
        for (int c = 0; c < 32; ++c) {
            const int j = j0 + c * 64;
            float p = 0.0f;
            if (j < jmax) p = __expf(mn - mv[c]);
            mv[c] = p;
            s += p;
        }
#pragma unroll
        for (int off = 32; off; off >>= 1) s += __shfl_xor(s, off);
        const float inv = 1.0f / s;
#pragma unroll
        for (int c = 0; c < 32; ++c) {
            const int j = j0 + c * 64;
            if (j < jmax) atomicAdd(&acc[j], mv[c] * inv);
        }
    }
    __syncthreads();
    float* ts = tsum + b * NTOK;
    for (int j = t; j < NTOK; j += 256) {
        const float v = acc[j];
        if (v != 0.0f) atomicAdd(&ts[j], v);
    }
}

__global__ void finalize_kernel(const float* __restrict__ tsum, float* __restrict__ out)
{
    const int b = blockIdx.y;
    const int j = blockIdx.x * 256 + threadIdx.x;
    if (j >= NTOK) return;
    float ts = tsum[b * NTOK + j];
    int steps = NTOK - 1 - j;
    if (steps > KSEG - 1) steps = KSEG - 1;
    float tc = (float)(j + 1) * (float)steps;
    if (j == NTOK - 1) { ts += (float)NTOK; tc += (float)NTOK; }
    out[b * NTOK + j] = ts / tc;
}

extern "C" void kernel_launch(void* const* d_in, const int* in_sizes, int n_in,
                              void* d_out, int out_size, void* d_ws, size_t ws_size,
                              hipStream_t stream)
{
    const float* x  = (const float*)d_in[0];
    const float* W0 = (const float*)d_in[1];
    const float* b0 = (const float*)d_in[2];
    const float* W1 = (const float*)d_in[3];
    const float* b1 = (const float*)d_in[4];
    float* out = (float*)d_out;

    char* ws = (char*)d_ws;
    size_t off = 0;
    auto alloc = [&](size_t bytes) -> void* {
        void* p = (void*)(ws + off);
        off += (bytes + 255) & ~(size_t)255;
        return p;
    };
    double* Rsc  = (double*)alloc((size_t)BATCH * ST2 * sizeof(double));
    float*  Dm   = (float*) alloc((size_t)BATCH * NTOK * NTOK * sizeof(float));
    float*  h    = (float*) alloc((size_t)BATCH * NTOK * HDIM * sizeof(float));
    float*  e    = (float*) alloc((size_t)BATCH * NTOK * EDIM * sizeof(float));
    float*  dvec = (float*) alloc((size_t)BATCH * NTOK * sizeof(float));
    double* dg   = (double*)alloc((size_t)BATCH * NP1 * sizeof(double));
    double* aux  = (double*)alloc((size_t)BATCH * STRIPS * NP1 * sizeof(double));
    float*  CA   = (float*) alloc((size_t)BATCH * NTOK * sizeof(float));
    float*  CB   = (float*) alloc((size_t)BATCH * NTOK * sizeof(float));
    float*  tsum = (float*) alloc((size_t)BATCH * NTOK * sizeof(float));
    int*    flags= (int*)   alloc((size_t)BATCH * DP_BX * 4 * sizeof(int));
    (void)ws_size; (void)in_sizes; (void)n_in; (void)out_size;

    hipMemsetAsync(tsum, 0, (size_t)BATCH * NTOK * sizeof(float), stream);
    hipMemsetAsync(flags, 0xFF, (size_t)BATCH * DP_BX * 4 * sizeof(int), stream);

    const int M = BATCH * NTOK;
    gemm_nt128s<<<dim3(HDIM / 128, M / 128, 2), 256, 0, stream>>>(
        x, FDIM, W0, FDIM, Dm, HDIM, M, FDIM / 2);
    combine_relu<<<dim3((M * HDIM / 4) / 256), 256, 0, stream>>>(
        Dm, Dm + (size_t)M * HDIM, b0, h);
    gemm_nt128s<<<dim3(EDIM / 128, M / 128, 4), 256, 0, stream>>>(
        h, HDIM, W1, HDIM, Dm, EDIM, M, HDIM / 4);
    rownorm_combine<<<dim3(M / 4), 256, 0, stream>>>(
        Dm, (size_t)M * EDIM, b1, e, dvec);
    gemm_corr<<<dim3(NTOK / 128, NTOK / 128, BATCH), 256, 0, stream>>>(e, Dm, dvec);
    sat_row_kernel<<<dim3(NTOK, BATCH), 256, 0, stream>>>(Dm, Rsc);
    satc1<<<dim3((NP1 + 255) / 256, STRIPS, BATCH), 256, 0, stream>>>(Rsc, aux);
    satc2_diag<<<dim3((NP1 + 255) / 256, BATCH), 256, 0, stream>>>(Rsc, aux, dg);
    satc3_bsum<<<dim3((NP1 + 255) / 256, STRIPS, BATCH), 256, 0, stream>>>(
        Rsc, aux, dg, Dm, CA);

    void* args[] = { (void*)&Dm, (void*)&CA, (void*)&CB, (void*)&tsum,
                     (void*)&flags, (void*)&out };
    hipError_t err = hipLaunchCooperativeKernel((const void*)dp_fused_kernel,
                                                dim3(DP_BX, BATCH), dim3(256),
                                                args, 0, stream);
    if (err != hipSuccess) {
        float* cp = CA; float* cn = CB;
        for (int kk = 1; kk < KSEG; ++kk) {
            dp_step_kernel<<<dim3(128, BATCH), 256, 0, stream>>>(Dm, cp, cn, tsum, kk);
            float* tmp = cp; cp = cn; cn = tmp;
        }
        finalize_kernel<<<dim3(NTOK / 256, BATCH), 256, 0, stream>>>(tsum, out);
    }
}